// Round 3
// baseline (707.127 us; speedup 1.0000x reference)
//
#include <hip/hip_runtime.h>
#include <hip/hip_bf16.h>
#include <math.h>

#define DIM 64

typedef _Float16 half_t;
typedef __attribute__((ext_vector_type(8))) _Float16 half8;
typedef __attribute__((ext_vector_type(4))) _Float16 h16x4;
typedef __attribute__((ext_vector_type(4))) float f32x4;

__device__ __forceinline__ half8 hmax8(half8 a, half8 b) {
    return __builtin_elementwise_max(a, b);   // v_pk_max_f16
}

// ---------------- CSR build (bucket-local; pairs packed src<<9 | dst&511) ----------------

__global__ void kbcnt(const int* __restrict__ ei, int E, int* __restrict__ gcnt) {
    __shared__ int h[256];
    int t = threadIdx.x;
    h[t] = 0;
    __syncthreads();
    for (int e = blockIdx.x * 256 + t; e < E; e += gridDim.x * 256)
        atomicAdd(&h[ei[E + e] >> 9], 1);
    __syncthreads();
    if (h[t]) atomicAdd(&gcnt[t], h[t]);
}

__global__ void kbscan(const int* __restrict__ gcnt, int* __restrict__ gbs,
                       int* __restrict__ gbc, int NB, int E,
                       int* __restrict__ rs, int N) {
    __shared__ int sm[256];
    int t = threadIdx.x;
    int v = (t < NB) ? gcnt[t] : 0;
    sm[t] = v;
    __syncthreads();
    for (int off = 1; off < 256; off <<= 1) {
        int add = (t >= off) ? sm[t - off] : 0;
        __syncthreads();
        sm[t] += add;
        __syncthreads();
    }
    int excl = sm[t] - v;
    if (t < NB) { gbs[t] = excl; gbc[t] = excl; }
    if (t == NB - 1) gbs[NB] = excl + v;    // == E
    if (t == 0) rs[N] = E;
}

__global__ void kbin(const int* __restrict__ ei, int E,
                     int* __restrict__ gbc, int* __restrict__ pairs, int NB) {
    __shared__ int hist[256];
    __shared__ int basep[256];
    const int t = threadIdx.x;
    const int c0 = blockIdx.x * 4096;
    hist[t] = 0;
    __syncthreads();
    int s[16], d[16];
#pragma unroll
    for (int i = 0; i < 16; ++i) {
        int e = c0 + i * 256 + t;
        if (e < E) {
            s[i] = ei[e];
            d[i] = ei[E + e];
            atomicAdd(&hist[d[i] >> 9], 1);
        } else d[i] = -1;
    }
    __syncthreads();
    if (t < NB) {
        basep[t] = atomicAdd(&gbc[t], hist[t]);
        hist[t] = 0;
    }
    __syncthreads();
#pragma unroll
    for (int i = 0; i < 16; ++i) {
        if (d[i] >= 0) {
            int b = d[i] >> 9;
            int off = atomicAdd(&hist[b], 1);
            pairs[basep[b] + off] = (s[i] << 9) | (d[i] & 511);
        }
    }
}

// ssrc stores BYTE offsets (src * 128) for the fp16 row gather.
__global__ void __launch_bounds__(256) kfinal(
        const int* __restrict__ pairs, const int* __restrict__ gbs,
        int* __restrict__ rs, int* __restrict__ ssrc, int N) {
    __shared__ int lcnt[512];
    __shared__ int lcur[512];
    __shared__ int ps[256];
    const int b = blockIdx.x;
    const int t = threadIdx.x;
    const int n0 = b << 9;
    const int e0 = gbs[b], e1 = gbs[b + 1];
    lcnt[t] = 0;
    lcnt[t + 256] = 0;
    __syncthreads();
    for (int e = e0 + t; e < e1; e += 256)
        atomicAdd(&lcnt[pairs[e] & 511], 1);
    __syncthreads();
    int c0 = lcnt[2 * t], c1 = lcnt[2 * t + 1];
    int sum = c0 + c1;
    ps[t] = sum;
    __syncthreads();
    for (int off = 1; off < 256; off <<= 1) {
        int add = (t >= off) ? ps[t - off] : 0;
        __syncthreads();
        ps[t] += add;
        __syncthreads();
    }
    int excl = ps[t] - sum;
    lcur[2 * t] = excl;
    lcur[2 * t + 1] = excl + c0;
    int n = n0 + 2 * t;
    if (n < N) rs[n] = e0 + excl;
    if (n + 1 < N) rs[n + 1] = e0 + excl + c0;
    __syncthreads();
    for (int e = e0 + t; e < e1; e += 256) {
        int p = pairs[e];
        int pos = atomicAdd(&lcur[p & 511], 1);
        ssrc[e0 + pos] = (int)((unsigned)p >> 9) << 7;   // byte offset of fp16 row
    }
}

// ---------------- fp32 x -> fp16 plane ----------------

__global__ void kcvt(const float* __restrict__ x, half_t* __restrict__ phi, int n4) {
    int i = blockIdx.x * blockDim.x + threadIdx.x;
    if (i < n4) {
        f32x4 v = ((const f32x4*)x)[i];
        h16x4 hi;
#pragma unroll
        for (int c = 0; c < 4; ++c) hi[c] = (half_t)v[c];
        ((h16x4*)phi)[i] = hi;
    }
}

// ---------------- weight prep: fp16 hi/lo MFMA B-fragments ----------------
// B[k][j], k in [0,128): k<64 -> Wl[j][k]; k>=64 -> Wr[j][k-64]
// frag f = (s*4+t)*2 (+1 for lo); element [lane][i]: k = s*32+(lane>>4)*8+i, j = t*16+(lane&15)

__global__ void kprepw(const float* __restrict__ Wl, const float* __restrict__ Wr,
                       half_t* __restrict__ Bf) {
    int id = blockIdx.x * blockDim.x + threadIdx.x;
    if (id >= 6 * 4 * 4 * 64 * 8) return;
    int i = id & 7;
    int lane = (id >> 3) & 63;
    int t = (id >> 9) & 3;
    int s = (id >> 11) & 3;
    int layer = id >> 13;
    int k = s * 32 + (lane >> 4) * 8 + i;
    int j = t * 16 + (lane & 15);
    float v = (k < 64) ? Wl[(layer * 64 + j) * 64 + k]
                       : Wr[(layer * 64 + j) * 64 + (k - 64)];
    half_t hi = (half_t)v;
    half_t lo = (half_t)(v - (float)hi);
    int f = (s * 4 + t) * 2;
    int base = layer * 16384 + f * 512 + lane * 8 + i;
    Bf[base] = hi;
    Bf[base + 512] = lo;
}

// ---------------- fused layer: gather-max into MFMA A-frags; weights in LDS ----------------
// A-frag layout for 16x16x32_f16: element [lane][i] = A[row = lane&15][k = (lane>>4)*8 + i].
// Lane (lrow, quad) owns the two 16B slices (quad*16) and (quad*16 + 64) of aggregated row
// m0+lrow; folds source-row slices with v_pk_max_f16 (clamped unroll-4, 8 loads in flight).
// The 32 B hi/lo fragments (32 KB) live in LDS, staged once per block: frees ~128 regs of
// persistent state -> <=128 VGPR -> 4 blocks/CU (16 waves/CU) to hide gather latency.
// Per-tile B reads: 32x ds_read_b128, contiguous 1KB per frag -> conflict-free.

__global__ void __launch_bounds__(256, 4) kfused(
        const half_t* __restrict__ hin, const int* __restrict__ rs,
        const int* __restrict__ soff, const half_t* __restrict__ Bf,
        const float* __restrict__ bias, float* __restrict__ out32,
        half_t* __restrict__ hout, int N, int last) {
    __shared__ half_t Bs[16384];                  // 32 KB: 32 frags x 512 halfs
    const int tid = threadIdx.x;
    const int lane = tid & 63;
    const int quad = lane >> 4;
    const int lrow = lane & 15;
    const int wv = (blockIdx.x * blockDim.x + tid) >> 6;
    const int nwv = (gridDim.x * blockDim.x) >> 6;
    const int ntiles = (N + 15) >> 4;

    // stage weights: 2048 half8 elements, 8 per thread, coalesced
    {
        const half8* __restrict__ Bg = (const half8*)Bf;
        half8* Bsh = (half8*)Bs;
#pragma unroll
        for (int i = 0; i < 8; ++i)
            Bsh[i * 256 + tid] = Bg[i * 256 + tid];
    }
    __syncthreads();
    const half8* __restrict__ Bls = (const half8*)Bs;

    float bs[4];
#pragma unroll
    for (int t = 0; t < 4; ++t) bs[t] = bias[t * 16 + lrow];

    const char* hq = (const char*)hin + quad * 16;   // + soff[e] = src*128 + quad*16
    const half_t NEG = (half_t)(-65504.0f);

    for (int tile = wv; tile < ntiles; tile += nwv) {
        const int m0 = tile << 4;
        int row = m0 + lrow;
        if (row >= N) row = N - 1;

        // root features (independent of gather; issue early)
        const char* ph = (const char*)hin + (size_t)row * 128 + quad * 16;
        half8 Hh0 = *(const half8*)(ph);
        half8 Hh1 = *(const half8*)(ph + 64);

        int beg = rs[row], end = rs[row + 1];
        int lastE = end - 1;
        half8 m0a = {NEG, NEG, NEG, NEG, NEG, NEG, NEG, NEG};
        half8 m1a = m0a, m2a = m0a, m3a = m0a;
        half8 m0b = m0a, m1b = m0a, m2b = m0a, m3b = m0a;
        for (int e = beg; e < end; e += 4) {    // clamped unroll-4
            int e1 = (e + 1 <= lastE) ? e + 1 : lastE;
            int e2 = (e + 2 <= lastE) ? e + 2 : lastE;
            int e3 = (e + 3 <= lastE) ? e + 3 : lastE;
            int o0 = soff[e], o1 = soff[e1], o2 = soff[e2], o3 = soff[e3];
            m0a = hmax8(m0a, *(const half8*)(hq + o0));
            m0b = hmax8(m0b, *(const half8*)(hq + o0 + 64));
            m1a = hmax8(m1a, *(const half8*)(hq + o1));
            m1b = hmax8(m1b, *(const half8*)(hq + o1 + 64));
            m2a = hmax8(m2a, *(const half8*)(hq + o2));
            m2b = hmax8(m2b, *(const half8*)(hq + o2 + 64));
            m3a = hmax8(m3a, *(const half8*)(hq + o3));
            m3b = hmax8(m3b, *(const half8*)(hq + o3 + 64));
        }
        half8 Aa0 = hmax8(hmax8(m0a, m1a), hmax8(m2a, m3a));
        half8 Aa1 = hmax8(hmax8(m0b, m1b), hmax8(m2b, m3b));
        if (end <= beg) {                       // no in-edges -> 0 (PyG convention)
            half8 z = {(half_t)0.f, (half_t)0.f, (half_t)0.f, (half_t)0.f,
                       (half_t)0.f, (half_t)0.f, (half_t)0.f, (half_t)0.f};
            Aa0 = z; Aa1 = z;
        }

        f32x4 acc[4] = {{0.f, 0.f, 0.f, 0.f}, {0.f, 0.f, 0.f, 0.f},
                        {0.f, 0.f, 0.f, 0.f}, {0.f, 0.f, 0.f, 0.f}};
#pragma unroll
        for (int t = 0; t < 4; ++t) {
            int f = t * 2;                      // (s*4+t)*2 for s=0..3 below
            acc[t] = __builtin_amdgcn_mfma_f32_16x16x32_f16(Aa0, Bls[(f     ) * 64 + lane],      acc[t], 0, 0, 0);
            acc[t] = __builtin_amdgcn_mfma_f32_16x16x32_f16(Aa0, Bls[(f     ) * 64 + 64 + lane], acc[t], 0, 0, 0);
            acc[t] = __builtin_amdgcn_mfma_f32_16x16x32_f16(Aa1, Bls[(f +  8) * 64 + lane],      acc[t], 0, 0, 0);
            acc[t] = __builtin_amdgcn_mfma_f32_16x16x32_f16(Aa1, Bls[(f +  8) * 64 + 64 + lane], acc[t], 0, 0, 0);
            acc[t] = __builtin_amdgcn_mfma_f32_16x16x32_f16(Hh0, Bls[(f + 16) * 64 + lane],      acc[t], 0, 0, 0);
            acc[t] = __builtin_amdgcn_mfma_f32_16x16x32_f16(Hh0, Bls[(f + 16) * 64 + 64 + lane], acc[t], 0, 0, 0);
            acc[t] = __builtin_amdgcn_mfma_f32_16x16x32_f16(Hh1, Bls[(f + 24) * 64 + lane],      acc[t], 0, 0, 0);
            acc[t] = __builtin_amdgcn_mfma_f32_16x16x32_f16(Hh1, Bls[(f + 24) * 64 + 64 + lane], acc[t], 0, 0, 0);
        }

        // C/D: col = t*16 + lrow, row = m0 + quad*4 + r
#pragma unroll
        for (int t = 0; t < 4; ++t) {
            int col = t * 16 + lrow;
#pragma unroll
            for (int r = 0; r < 4; ++r) {
                int orow = m0 + quad * 4 + r;
                if (orow < N) {
                    float v = acc[t][r] + bs[t];
                    if (!last) {
                        v = fmaxf(v, 0.0f);
                        hout[(size_t)orow * DIM + col] = (half_t)v;
                    } else {
                        out32[(size_t)orow * DIM + col] = v;
                    }
                }
            }
        }
    }
}

// ---------------- host ----------------

extern "C" void kernel_launch(void* const* d_in, const int* in_sizes, int n_in,
                              void* d_out, int out_size, void* d_ws, size_t ws_size,
                              hipStream_t stream) {
    const float* x  = (const float*)d_in[0];
    const int*   ei = (const int*)d_in[1];
    const float* Wl = (const float*)d_in[2];
    const float* bl = (const float*)d_in[3];
    const float* Wr = (const float*)d_in[4];
    int N = in_sizes[0] / DIM;
    int E = in_sizes[1] / 2;

    size_t nd = (size_t)N * DIM;
    half_t* p0    = (half_t*)d_ws;           // fp16 h ping
    half_t* p1    = p0 + nd;                 // fp16 h pong
    half_t* scratch = p1 + nd;               // nd halfs; holds `pairs` during CSR build
    int*    rs    = (int*)(scratch + nd);    // N+1 used, N+4 reserved
    int*    ssrc  = rs + (N + 4);            // byte offsets
    int*    gcnt  = ssrc + E;                // 256
    int*    gbs   = gcnt + 256;              // NB+1 (260 reserved)
    int*    gbc   = gbs + 260;               // 256
    half_t* Bf    = (half_t*)(gbc + 256);    // 6 layers * 16384 halfs

    int NB = (N + 511) >> 9;                 // 196 for N=100000
    int* pairs = (int*)scratch;

    hipMemsetAsync(gcnt, 0, 256 * sizeof(int), stream);
    kbcnt<<<640, 256, 0, stream>>>(ei, E, gcnt);
    kbscan<<<1, 256, 0, stream>>>(gcnt, gbs, gbc, NB, E, rs, N);
    kbin<<<(E + 4095) / 4096, 256, 0, stream>>>(ei, E, gbc, pairs, NB);
    kfinal<<<NB, 256, 0, stream>>>(pairs, gbs, rs, ssrc, N);
    kprepw<<<(6 * 4 * 4 * 64 * 8 + 255) / 256, 256, 0, stream>>>(Wl, Wr, Bf);
    kcvt<<<((int)(nd / 4) + 255) / 256, 256, 0, stream>>>(x, p0, (int)(nd / 4));

    int ntiles = (N + 15) >> 4;
    int gblocks = (ntiles + 3) >> 2;         // ~1 tile per wave; queued blocks backfill
    for (int l = 0; l < 6; ++l) {
        half_t* ih = (l & 1) ? p1 : p0;
        half_t* oh = (l & 1) ? p0 : p1;
        int last = (l == 5);
        kfused<<<gblocks, 256, 0, stream>>>(ih, rs, ssrc, Bf + l * 16384, bl + l * 64,
                                            (float*)d_out, oh, N, last);
    }
}

// Round 4
// 636.689 us; speedup vs baseline: 1.1106x; 1.1106x over previous
//
#include <hip/hip_runtime.h>
#include <hip/hip_bf16.h>
#include <math.h>

#define DIM 64

typedef _Float16 half_t;
typedef __attribute__((ext_vector_type(8))) _Float16 half8;
typedef __attribute__((ext_vector_type(4))) _Float16 h16x4;
typedef __attribute__((ext_vector_type(4))) float f32x4;

__device__ __forceinline__ half8 hmax8(half8 a, half8 b) {
    return __builtin_elementwise_max(a, b);   // v_pk_max_f16
}

// ---------------- CSR build (bucket-local; pairs packed src<<9 | dst&511) ----------------

__global__ void kbcnt(const int* __restrict__ ei, int E, int* __restrict__ gcnt) {
    __shared__ int h[256];
    int t = threadIdx.x;
    h[t] = 0;
    __syncthreads();
    for (int e = blockIdx.x * 256 + t; e < E; e += gridDim.x * 256)
        atomicAdd(&h[ei[E + e] >> 9], 1);
    __syncthreads();
    if (h[t]) atomicAdd(&gcnt[t], h[t]);
}

__global__ void kbscan(const int* __restrict__ gcnt, int* __restrict__ gbs,
                       int* __restrict__ gbc, int NB, int E,
                       int* __restrict__ rs, int N) {
    __shared__ int sm[256];
    int t = threadIdx.x;
    int v = (t < NB) ? gcnt[t] : 0;
    sm[t] = v;
    __syncthreads();
    for (int off = 1; off < 256; off <<= 1) {
        int add = (t >= off) ? sm[t - off] : 0;
        __syncthreads();
        sm[t] += add;
        __syncthreads();
    }
    int excl = sm[t] - v;
    if (t < NB) { gbs[t] = excl; gbc[t] = excl; }
    if (t == NB - 1) gbs[NB] = excl + v;    // == E
    if (t == 0) rs[N] = E;
}

__global__ void kbin(const int* __restrict__ ei, int E,
                     int* __restrict__ gbc, int* __restrict__ pairs, int NB) {
    __shared__ int hist[256];
    __shared__ int basep[256];
    const int t = threadIdx.x;
    const int c0 = blockIdx.x * 4096;
    hist[t] = 0;
    __syncthreads();
    int s[16], d[16];
#pragma unroll
    for (int i = 0; i < 16; ++i) {
        int e = c0 + i * 256 + t;
        if (e < E) {
            s[i] = ei[e];
            d[i] = ei[E + e];
            atomicAdd(&hist[d[i] >> 9], 1);
        } else d[i] = -1;
    }
    __syncthreads();
    if (t < NB) {
        basep[t] = atomicAdd(&gbc[t], hist[t]);
        hist[t] = 0;
    }
    __syncthreads();
#pragma unroll
    for (int i = 0; i < 16; ++i) {
        if (d[i] >= 0) {
            int b = d[i] >> 9;
            int off = atomicAdd(&hist[b], 1);
            pairs[basep[b] + off] = (s[i] << 9) | (d[i] & 511);
        }
    }
}

// ssrc stores BYTE offsets (src * 128) for the fp16 row gather.
__global__ void __launch_bounds__(256) kfinal(
        const int* __restrict__ pairs, const int* __restrict__ gbs,
        int* __restrict__ rs, int* __restrict__ ssrc, int N) {
    __shared__ int lcnt[512];
    __shared__ int lcur[512];
    __shared__ int ps[256];
    const int b = blockIdx.x;
    const int t = threadIdx.x;
    const int n0 = b << 9;
    const int e0 = gbs[b], e1 = gbs[b + 1];
    lcnt[t] = 0;
    lcnt[t + 256] = 0;
    __syncthreads();
    for (int e = e0 + t; e < e1; e += 256)
        atomicAdd(&lcnt[pairs[e] & 511], 1);
    __syncthreads();
    int c0 = lcnt[2 * t], c1 = lcnt[2 * t + 1];
    int sum = c0 + c1;
    ps[t] = sum;
    __syncthreads();
    for (int off = 1; off < 256; off <<= 1) {
        int add = (t >= off) ? ps[t - off] : 0;
        __syncthreads();
        ps[t] += add;
        __syncthreads();
    }
    int excl = ps[t] - sum;
    lcur[2 * t] = excl;
    lcur[2 * t + 1] = excl + c0;
    int n = n0 + 2 * t;
    if (n < N) rs[n] = e0 + excl;
    if (n + 1 < N) rs[n + 1] = e0 + excl + c0;
    __syncthreads();
    for (int e = e0 + t; e < e1; e += 256) {
        int p = pairs[e];
        int pos = atomicAdd(&lcur[p & 511], 1);
        ssrc[e0 + pos] = (int)((unsigned)p >> 9) << 7;   // byte offset of fp16 row
    }
}

// ---------------- fp32 x -> fp16 plane ----------------

__global__ void kcvt(const float* __restrict__ x, half_t* __restrict__ phi, int n4) {
    int i = blockIdx.x * blockDim.x + threadIdx.x;
    if (i < n4) {
        f32x4 v = ((const f32x4*)x)[i];
        h16x4 hi;
#pragma unroll
        for (int c = 0; c < 4; ++c) hi[c] = (half_t)v[c];
        ((h16x4*)phi)[i] = hi;
    }
}

// ---------------- weight prep: fp16 hi/lo MFMA B-fragments ----------------
// B[k][j], k in [0,128): k<64 -> Wl[j][k]; k>=64 -> Wr[j][k-64]
// frag f = (s*4+t)*2 (+1 for lo); element [lane][i]: k = s*32+(lane>>4)*8+i, j = t*16+(lane&15)

__global__ void kprepw(const float* __restrict__ Wl, const float* __restrict__ Wr,
                       half_t* __restrict__ Bf) {
    int id = blockIdx.x * blockDim.x + threadIdx.x;
    if (id >= 6 * 4 * 4 * 64 * 8) return;
    int i = id & 7;
    int lane = (id >> 3) & 63;
    int t = (id >> 9) & 3;
    int s = (id >> 11) & 3;
    int layer = id >> 13;
    int k = s * 32 + (lane >> 4) * 8 + i;
    int j = t * 16 + (lane & 15);
    float v = (k < 64) ? Wl[(layer * 64 + j) * 64 + k]
                       : Wr[(layer * 64 + j) * 64 + (k - 64)];
    half_t hi = (half_t)v;
    half_t lo = (half_t)(v - (float)hi);
    int f = (s * 4 + t) * 2;
    int base = layer * 16384 + f * 512 + lane * 8 + i;
    Bf[base] = hi;
    Bf[base + 512] = lo;
}

// ---------------- fused layer: gather-max into MFMA A-frags; weights in LDS ----------------
// A-frag layout for 16x16x32_f16: element [lane][i] = A[row = lane&15][k = (lane>>4)*8 + i].
// Lane (lrow, quad) owns the two 16B slices (quad*16) and (quad*16 + 64) of aggregated row
// m0+lrow; folds source-row slices with v_pk_max_f16 (clamped unroll-4, 8 loads in flight).
// The 32 B hi/lo fragments (32 KB) live in LDS, staged once per block.
// launch_bounds(256,3): ~170 regs/wave -> NO SPILL (the (256,4)=128-reg variant spilled:
// WRITE_SIZE 25->134 MB of scratch traffic, 2x slower). 3 blocks/CU = 12 waves/CU.

__global__ void __launch_bounds__(256, 3) kfused(
        const half_t* __restrict__ hin, const int* __restrict__ rs,
        const int* __restrict__ soff, const half_t* __restrict__ Bf,
        const float* __restrict__ bias, float* __restrict__ out32,
        half_t* __restrict__ hout, int N, int last) {
    __shared__ half_t Bs[16384];                  // 32 KB: 32 frags x 512 halfs
    const int tid = threadIdx.x;
    const int lane = tid & 63;
    const int quad = lane >> 4;
    const int lrow = lane & 15;
    const int wv = (blockIdx.x * blockDim.x + tid) >> 6;
    const int nwv = (gridDim.x * blockDim.x) >> 6;
    const int ntiles = (N + 15) >> 4;

    // stage weights: 2048 half8 elements, 8 per thread, coalesced
    {
        const half8* __restrict__ Bg = (const half8*)Bf;
        half8* Bsh = (half8*)Bs;
#pragma unroll
        for (int i = 0; i < 8; ++i)
            Bsh[i * 256 + tid] = Bg[i * 256 + tid];
    }
    __syncthreads();
    const half8* __restrict__ Bls = (const half8*)Bs;

    float bs[4];
#pragma unroll
    for (int t = 0; t < 4; ++t) bs[t] = bias[t * 16 + lrow];

    const char* hq = (const char*)hin + quad * 16;   // + soff[e] = src*128 + quad*16
    const half_t NEG = (half_t)(-65504.0f);

    for (int tile = wv; tile < ntiles; tile += nwv) {
        const int m0 = tile << 4;
        int row = m0 + lrow;
        if (row >= N) row = N - 1;

        // root features (independent of gather; issue early)
        const char* ph = (const char*)hin + (size_t)row * 128 + quad * 16;
        half8 Hh0 = *(const half8*)(ph);
        half8 Hh1 = *(const half8*)(ph + 64);

        int beg = rs[row], end = rs[row + 1];
        int lastE = end - 1;
        half8 m0a = {NEG, NEG, NEG, NEG, NEG, NEG, NEG, NEG};
        half8 m1a = m0a, m2a = m0a, m3a = m0a;
        half8 m0b = m0a, m1b = m0a, m2b = m0a, m3b = m0a;
        for (int e = beg; e < end; e += 4) {    // clamped unroll-4
            int e1 = (e + 1 <= lastE) ? e + 1 : lastE;
            int e2 = (e + 2 <= lastE) ? e + 2 : lastE;
            int e3 = (e + 3 <= lastE) ? e + 3 : lastE;
            int o0 = soff[e], o1 = soff[e1], o2 = soff[e2], o3 = soff[e3];
            m0a = hmax8(m0a, *(const half8*)(hq + o0));
            m0b = hmax8(m0b, *(const half8*)(hq + o0 + 64));
            m1a = hmax8(m1a, *(const half8*)(hq + o1));
            m1b = hmax8(m1b, *(const half8*)(hq + o1 + 64));
            m2a = hmax8(m2a, *(const half8*)(hq + o2));
            m2b = hmax8(m2b, *(const half8*)(hq + o2 + 64));
            m3a = hmax8(m3a, *(const half8*)(hq + o3));
            m3b = hmax8(m3b, *(const half8*)(hq + o3 + 64));
        }
        half8 Aa0 = hmax8(hmax8(m0a, m1a), hmax8(m2a, m3a));
        half8 Aa1 = hmax8(hmax8(m0b, m1b), hmax8(m2b, m3b));
        if (end <= beg) {                       // no in-edges -> 0 (PyG convention)
            half8 z = {(half_t)0.f, (half_t)0.f, (half_t)0.f, (half_t)0.f,
                       (half_t)0.f, (half_t)0.f, (half_t)0.f, (half_t)0.f};
            Aa0 = z; Aa1 = z;
        }

        f32x4 acc[4] = {{0.f, 0.f, 0.f, 0.f}, {0.f, 0.f, 0.f, 0.f},
                        {0.f, 0.f, 0.f, 0.f}, {0.f, 0.f, 0.f, 0.f}};
#pragma unroll
        for (int t = 0; t < 4; ++t) {
            int f = t * 2;                      // (s*4+t)*2 for s=0..3 below
            acc[t] = __builtin_amdgcn_mfma_f32_16x16x32_f16(Aa0, Bls[(f     ) * 64 + lane],      acc[t], 0, 0, 0);
            acc[t] = __builtin_amdgcn_mfma_f32_16x16x32_f16(Aa0, Bls[(f     ) * 64 + 64 + lane], acc[t], 0, 0, 0);
            acc[t] = __builtin_amdgcn_mfma_f32_16x16x32_f16(Aa1, Bls[(f +  8) * 64 + lane],      acc[t], 0, 0, 0);
            acc[t] = __builtin_amdgcn_mfma_f32_16x16x32_f16(Aa1, Bls[(f +  8) * 64 + 64 + lane], acc[t], 0, 0, 0);
            acc[t] = __builtin_amdgcn_mfma_f32_16x16x32_f16(Hh0, Bls[(f + 16) * 64 + lane],      acc[t], 0, 0, 0);
            acc[t] = __builtin_amdgcn_mfma_f32_16x16x32_f16(Hh0, Bls[(f + 16) * 64 + 64 + lane], acc[t], 0, 0, 0);
            acc[t] = __builtin_amdgcn_mfma_f32_16x16x32_f16(Hh1, Bls[(f + 24) * 64 + lane],      acc[t], 0, 0, 0);
            acc[t] = __builtin_amdgcn_mfma_f32_16x16x32_f16(Hh1, Bls[(f + 24) * 64 + 64 + lane], acc[t], 0, 0, 0);
        }

        // C/D: col = t*16 + lrow, row = m0 + quad*4 + r
#pragma unroll
        for (int t = 0; t < 4; ++t) {
            int col = t * 16 + lrow;
#pragma unroll
            for (int r = 0; r < 4; ++r) {
                int orow = m0 + quad * 4 + r;
                if (orow < N) {
                    float v = acc[t][r] + bs[t];
                    if (!last) {
                        v = fmaxf(v, 0.0f);
                        hout[(size_t)orow * DIM + col] = (half_t)v;
                    } else {
                        out32[(size_t)orow * DIM + col] = v;
                    }
                }
            }
        }
    }
}

// ---------------- host ----------------

extern "C" void kernel_launch(void* const* d_in, const int* in_sizes, int n_in,
                              void* d_out, int out_size, void* d_ws, size_t ws_size,
                              hipStream_t stream) {
    const float* x  = (const float*)d_in[0];
    const int*   ei = (const int*)d_in[1];
    const float* Wl = (const float*)d_in[2];
    const float* bl = (const float*)d_in[3];
    const float* Wr = (const float*)d_in[4];
    int N = in_sizes[0] / DIM;
    int E = in_sizes[1] / 2;

    size_t nd = (size_t)N * DIM;
    half_t* p0    = (half_t*)d_ws;           // fp16 h ping
    half_t* p1    = p0 + nd;                 // fp16 h pong
    half_t* scratch = p1 + nd;               // nd halfs; holds `pairs` during CSR build
    int*    rs    = (int*)(scratch + nd);    // N+1 used, N+4 reserved
    int*    ssrc  = rs + (N + 4);            // byte offsets
    int*    gcnt  = ssrc + E;                // 256
    int*    gbs   = gcnt + 256;              // NB+1 (260 reserved)
    int*    gbc   = gbs + 260;               // 256
    half_t* Bf    = (half_t*)(gbc + 256);    // 6 layers * 16384 halfs

    int NB = (N + 511) >> 9;                 // 196 for N=100000
    int* pairs = (int*)scratch;

    hipMemsetAsync(gcnt, 0, 256 * sizeof(int), stream);
    kbcnt<<<640, 256, 0, stream>>>(ei, E, gcnt);
    kbscan<<<1, 256, 0, stream>>>(gcnt, gbs, gbc, NB, E, rs, N);
    kbin<<<(E + 4095) / 4096, 256, 0, stream>>>(ei, E, gbc, pairs, NB);
    kfinal<<<NB, 256, 0, stream>>>(pairs, gbs, rs, ssrc, N);
    kprepw<<<(6 * 4 * 4 * 64 * 8 + 255) / 256, 256, 0, stream>>>(Wl, Wr, Bf);
    kcvt<<<((int)(nd / 4) + 255) / 256, 256, 0, stream>>>(x, p0, (int)(nd / 4));

    int ntiles = (N + 15) >> 4;
    int gblocks = (ntiles + 3) >> 2;         // ~1 tile per wave; queued blocks backfill
    for (int l = 0; l < 6; ++l) {
        half_t* ih = (l & 1) ? p1 : p0;
        half_t* oh = (l & 1) ? p0 : p1;
        int last = (l == 5);
        kfused<<<gblocks, 256, 0, stream>>>(ih, rs, ssrc, Bf + l * 16384, bl + l * 64,
                                            (float*)d_out, oh, N, last);
    }
}

// Round 6
// 583.442 us; speedup vs baseline: 1.2120x; 1.0913x over previous
//
#include <hip/hip_runtime.h>
#include <hip/hip_bf16.h>
#include <math.h>

#define DIM 64

typedef _Float16 half_t;
typedef __attribute__((ext_vector_type(8))) _Float16 half8;
typedef __attribute__((ext_vector_type(4))) _Float16 h16x4;
typedef __attribute__((ext_vector_type(4))) float f32x4;

__device__ __forceinline__ half8 hmax8(half8 a, half8 b) {
    return __builtin_elementwise_max(a, b);   // v_pk_max_f16
}

// ---------------- CSR build (bucket-local; pairs packed src<<9 | dst&511) ----------------

__global__ void kbcnt(const int* __restrict__ ei, int E, int* __restrict__ gcnt) {
    __shared__ int h[256];
    int t = threadIdx.x;
    h[t] = 0;
    __syncthreads();
    for (int e = blockIdx.x * 256 + t; e < E; e += gridDim.x * 256)
        atomicAdd(&h[ei[E + e] >> 9], 1);
    __syncthreads();
    if (h[t]) atomicAdd(&gcnt[t], h[t]);
}

__global__ void kbscan(const int* __restrict__ gcnt, int* __restrict__ gbs,
                       int* __restrict__ gbc, int NB, int E,
                       int* __restrict__ rs, int N) {
    __shared__ int sm[256];
    int t = threadIdx.x;
    int v = (t < NB) ? gcnt[t] : 0;
    sm[t] = v;
    __syncthreads();
    for (int off = 1; off < 256; off <<= 1) {
        int add = (t >= off) ? sm[t - off] : 0;
        __syncthreads();
        sm[t] += add;
        __syncthreads();
    }
    int excl = sm[t] - v;
    if (t < NB) { gbs[t] = excl; gbc[t] = excl; }
    if (t == NB - 1) gbs[NB] = excl + v;    // == E
    if (t == 0) rs[N] = E;
}

__global__ void kbin(const int* __restrict__ ei, int E,
                     int* __restrict__ gbc, int* __restrict__ pairs, int NB) {
    __shared__ int hist[256];
    __shared__ int basep[256];
    const int t = threadIdx.x;
    const int c0 = blockIdx.x * 4096;
    hist[t] = 0;
    __syncthreads();
    int s[16], d[16];
#pragma unroll
    for (int i = 0; i < 16; ++i) {
        int e = c0 + i * 256 + t;
        if (e < E) {
            s[i] = ei[e];
            d[i] = ei[E + e];
            atomicAdd(&hist[d[i] >> 9], 1);
        } else d[i] = -1;
    }
    __syncthreads();
    if (t < NB) {
        basep[t] = atomicAdd(&gbc[t], hist[t]);
        hist[t] = 0;
    }
    __syncthreads();
#pragma unroll
    for (int i = 0; i < 16; ++i) {
        if (d[i] >= 0) {
            int b = d[i] >> 9;
            int off = atomicAdd(&hist[b], 1);
            pairs[basep[b] + off] = (s[i] << 9) | (d[i] & 511);
        }
    }
}

// ssrc stores BYTE offsets (src * 128) for the fp16 row gather.
__global__ void __launch_bounds__(256) kfinal(
        const int* __restrict__ pairs, const int* __restrict__ gbs,
        int* __restrict__ rs, int* __restrict__ ssrc, int N) {
    __shared__ int lcnt[512];
    __shared__ int lcur[512];
    __shared__ int ps[256];
    const int b = blockIdx.x;
    const int t = threadIdx.x;
    const int n0 = b << 9;
    const int e0 = gbs[b], e1 = gbs[b + 1];
    lcnt[t] = 0;
    lcnt[t + 256] = 0;
    __syncthreads();
    for (int e = e0 + t; e < e1; e += 256)
        atomicAdd(&lcnt[pairs[e] & 511], 1);
    __syncthreads();
    int c0 = lcnt[2 * t], c1 = lcnt[2 * t + 1];
    int sum = c0 + c1;
    ps[t] = sum;
    __syncthreads();
    for (int off = 1; off < 256; off <<= 1) {
        int add = (t >= off) ? ps[t - off] : 0;
        __syncthreads();
        ps[t] += add;
        __syncthreads();
    }
    int excl = ps[t] - sum;
    lcur[2 * t] = excl;
    lcur[2 * t + 1] = excl + c0;
    int n = n0 + 2 * t;
    if (n < N) rs[n] = e0 + excl;
    if (n + 1 < N) rs[n + 1] = e0 + excl + c0;
    __syncthreads();
    for (int e = e0 + t; e < e1; e += 256) {
        int p = pairs[e];
        int pos = atomicAdd(&lcur[p & 511], 1);
        ssrc[e0 + pos] = (int)((unsigned)p >> 9) << 7;   // byte offset of fp16 row
    }
}

// ---------------- fp32 x -> fp16 plane ----------------

__global__ void kcvt(const float* __restrict__ x, half_t* __restrict__ phi, int n4) {
    int i = blockIdx.x * blockDim.x + threadIdx.x;
    if (i < n4) {
        f32x4 v = ((const f32x4*)x)[i];
        h16x4 hi;
#pragma unroll
        for (int c = 0; c < 4; ++c) hi[c] = (half_t)v[c];
        ((h16x4*)phi)[i] = hi;
    }
}

// ---------------- weight prep: fp16 hi/lo MFMA B-fragments ----------------
// B[k][j], k in [0,128): k<64 -> Wl[j][k]; k>=64 -> Wr[j][k-64]
// frag f = (s*4+t)*2 (+1 for lo); element [lane][i]: k = s*32+(lane>>4)*8+i, j = t*16+(lane&15)

__global__ void kprepw(const float* __restrict__ Wl, const float* __restrict__ Wr,
                       half_t* __restrict__ Bf) {
    int id = blockIdx.x * blockDim.x + threadIdx.x;
    if (id >= 6 * 4 * 4 * 64 * 8) return;
    int i = id & 7;
    int lane = (id >> 3) & 63;
    int t = (id >> 9) & 3;
    int s = (id >> 11) & 3;
    int layer = id >> 13;
    int k = s * 32 + (lane >> 4) * 8 + i;
    int j = t * 16 + (lane & 15);
    float v = (k < 64) ? Wl[(layer * 64 + j) * 64 + k]
                       : Wr[(layer * 64 + j) * 64 + (k - 64)];
    half_t hi = (half_t)v;
    half_t lo = (half_t)(v - (float)hi);
    int f = (s * 4 + t) * 2;
    int base = layer * 16384 + f * 512 + lane * 8 + i;
    Bf[base] = hi;
    Bf[base + 512] = lo;
}

// ---------------- fused layer: gather-max into MFMA A-frags; weights in LDS ----------------
// A-frag layout for 16x16x32_f16: element [lane][i] = A[row = lane&15][k = (lane>>4)*8 + i].
// Lane (lrow, quad) owns the two 16B slices (quad*16) and (quad*16 + 64) of aggregated row
// m0+lrow; folds source-row slices with v_pk_max_f16.
// REGISTER BUDGET (measured r3/r4): with MFMA present the allocator splits the per-wave
// unified budget EVENLY into arch-VGPR / AGPR halves. launch_bounds(256,3) -> 170/wave ->
// 84 arch VGPRs. Gather loop must fit 84 arch regs: unroll-2 (4 accums + 4 in-flight loads)
// + root-feature loads deferred to after the loop ~= 60 arch regs -> no spill, 12 waves/CU.
// (unroll-4 needed ~80+ and spilled: r4 WRITE_SIZE 68.7MB vs 12.6MB true output.)

__global__ void __launch_bounds__(256, 3) kfused(
        const half_t* __restrict__ hin, const int* __restrict__ rs,
        const int* __restrict__ soff, const half_t* __restrict__ Bf,
        const float* __restrict__ bias, float* __restrict__ out32,
        half_t* __restrict__ hout, int N, int last) {
    __shared__ half_t Bs[16384];                  // 32 KB: 32 frags x 512 halfs
    const int tid = threadIdx.x;
    const int lane = tid & 63;
    const int quad = lane >> 4;
    const int lrow = lane & 15;
    const int wv = (blockIdx.x * blockDim.x + tid) >> 6;
    const int nwv = (gridDim.x * blockDim.x) >> 6;
    const int ntiles = (N + 15) >> 4;

    // stage weights: 2048 half8 elements, 8 per thread, coalesced
    {
        const half8* __restrict__ Bg = (const half8*)Bf;
        half8* Bsh = (half8*)Bs;
#pragma unroll
        for (int i = 0; i < 8; ++i)
            Bsh[i * 256 + tid] = Bg[i * 256 + tid];
    }
    __syncthreads();
    const half8* __restrict__ Bls = (const half8*)Bs;

    const char* hq = (const char*)hin + quad * 16;   // + soff[e] = src*128 + quad*16
    const half_t NEG = (half_t)(-65504.0f);

    for (int tile = wv; tile < ntiles; tile += nwv) {
        const int m0 = tile << 4;
        int row = m0 + lrow;
        if (row >= N) row = N - 1;

        int beg = rs[row], end = rs[row + 1];
        int lastE = end - 1;
        half8 m0a = {NEG, NEG, NEG, NEG, NEG, NEG, NEG, NEG};
        half8 m1a = m0a, m0b = m0a, m1b = m0a;
        for (int e = beg; e < end; e += 2) {    // clamped unroll-2: re-max of seen edge is no-op
            int e1 = (e + 1 <= lastE) ? e + 1 : lastE;
            int o0 = soff[e], o1 = soff[e1];
            m0a = hmax8(m0a, *(const half8*)(hq + o0));
            m0b = hmax8(m0b, *(const half8*)(hq + o0 + 64));
            m1a = hmax8(m1a, *(const half8*)(hq + o1));
            m1b = hmax8(m1b, *(const half8*)(hq + o1 + 64));
        }
        half8 Aa0 = hmax8(m0a, m1a);
        half8 Aa1 = hmax8(m0b, m1b);
        if (end <= beg) {                       // no in-edges -> 0 (PyG convention)
            half8 z = {(half_t)0.f, (half_t)0.f, (half_t)0.f, (half_t)0.f,
                       (half_t)0.f, (half_t)0.f, (half_t)0.f, (half_t)0.f};
            Aa0 = z; Aa1 = z;
        }

        // root features (loaded after gather to keep loop register pressure low)
        const char* ph = (const char*)hin + (size_t)row * 128 + quad * 16;
        half8 Hh0 = *(const half8*)(ph);
        half8 Hh1 = *(const half8*)(ph + 64);

        f32x4 acc[4] = {{0.f, 0.f, 0.f, 0.f}, {0.f, 0.f, 0.f, 0.f},
                        {0.f, 0.f, 0.f, 0.f}, {0.f, 0.f, 0.f, 0.f}};
#pragma unroll
        for (int t = 0; t < 4; ++t) {
            int f = t * 2;                      // (s*4+t)*2 for s=0..3 below
            acc[t] = __builtin_amdgcn_mfma_f32_16x16x32_f16(Aa0, Bls[(f     ) * 64 + lane],      acc[t], 0, 0, 0);
            acc[t] = __builtin_amdgcn_mfma_f32_16x16x32_f16(Aa0, Bls[(f     ) * 64 + 64 + lane], acc[t], 0, 0, 0);
            acc[t] = __builtin_amdgcn_mfma_f32_16x16x32_f16(Aa1, Bls[(f +  8) * 64 + lane],      acc[t], 0, 0, 0);
            acc[t] = __builtin_amdgcn_mfma_f32_16x16x32_f16(Aa1, Bls[(f +  8) * 64 + 64 + lane], acc[t], 0, 0, 0);
            acc[t] = __builtin_amdgcn_mfma_f32_16x16x32_f16(Hh0, Bls[(f + 16) * 64 + lane],      acc[t], 0, 0, 0);
            acc[t] = __builtin_amdgcn_mfma_f32_16x16x32_f16(Hh0, Bls[(f + 16) * 64 + 64 + lane], acc[t], 0, 0, 0);
            acc[t] = __builtin_amdgcn_mfma_f32_16x16x32_f16(Hh1, Bls[(f + 24) * 64 + lane],      acc[t], 0, 0, 0);
            acc[t] = __builtin_amdgcn_mfma_f32_16x16x32_f16(Hh1, Bls[(f + 24) * 64 + 64 + lane], acc[t], 0, 0, 0);
        }

        // C/D: col = t*16 + lrow, row = m0 + quad*4 + r
#pragma unroll
        for (int t = 0; t < 4; ++t) {
            int col = t * 16 + lrow;
            float bsv = bias[t * 16 + lrow];
#pragma unroll
            for (int r = 0; r < 4; ++r) {
                int orow = m0 + quad * 4 + r;
                if (orow < N) {
                    float v = acc[t][r] + bsv;
                    if (!last) {
                        v = fmaxf(v, 0.0f);
                        hout[(size_t)orow * DIM + col] = (half_t)v;
                    } else {
                        out32[(size_t)orow * DIM + col] = v;
                    }
                }
            }
        }
    }
}

// ---------------- host ----------------

extern "C" void kernel_launch(void* const* d_in, const int* in_sizes, int n_in,
                              void* d_out, int out_size, void* d_ws, size_t ws_size,
                              hipStream_t stream) {
    const float* x  = (const float*)d_in[0];
    const int*   ei = (const int*)d_in[1];
    const float* Wl = (const float*)d_in[2];
    const float* bl = (const float*)d_in[3];
    const float* Wr = (const float*)d_in[4];
    int N = in_sizes[0] / DIM;
    int E = in_sizes[1] / 2;

    size_t nd = (size_t)N * DIM;
    half_t* p0    = (half_t*)d_ws;           // fp16 h ping
    half_t* p1    = p0 + nd;                 // fp16 h pong
    half_t* scratch = p1 + nd;               // nd halfs; holds `pairs` during CSR build
    int*    rs    = (int*)(scratch + nd);    // N+1 used, N+4 reserved
    int*    ssrc  = rs + (N + 4);            // byte offsets
    int*    gcnt  = ssrc + E;                // 256
    int*    gbs   = gcnt + 256;              // NB+1 (260 reserved)
    int*    gbc   = gbs + 260;               // 256
    half_t* Bf    = (half_t*)(gbc + 256);    // 6 layers * 16384 halfs

    int NB = (N + 511) >> 9;                 // 196 for N=100000
    int* pairs = (int*)scratch;

    hipMemsetAsync(gcnt, 0, 256 * sizeof(int), stream);
    kbcnt<<<640, 256, 0, stream>>>(ei, E, gcnt);
    kbscan<<<1, 256, 0, stream>>>(gcnt, gbs, gbc, NB, E, rs, N);
    kbin<<<(E + 4095) / 4096, 256, 0, stream>>>(ei, E, gbc, pairs, NB);
    kfinal<<<NB, 256, 0, stream>>>(pairs, gbs, rs, ssrc, N);
    kprepw<<<(6 * 4 * 4 * 64 * 8 + 255) / 256, 256, 0, stream>>>(Wl, Wr, Bf);
    kcvt<<<((int)(nd / 4) + 255) / 256, 256, 0, stream>>>(x, p0, (int)(nd / 4));

    int ntiles = (N + 15) >> 4;
    int gblocks = (ntiles + 3) >> 2;         // ~1 tile per wave; queued blocks backfill
    for (int l = 0; l < 6; ++l) {
        half_t* ih = (l & 1) ? p1 : p0;
        half_t* oh = (l & 1) ? p0 : p1;
        int last = (l == 5);
        kfused<<<gblocks, 256, 0, stream>>>(ih, rs, ssrc, Bf + l * 16384, bl + l * 64,
                                            (float*)d_out, oh, N, last);
    }
}

// Round 7
// 566.630 us; speedup vs baseline: 1.2480x; 1.0297x over previous
//
#include <hip/hip_runtime.h>
#include <hip/hip_bf16.h>
#include <math.h>

#define DIM 64

typedef _Float16 half_t;
typedef __attribute__((ext_vector_type(8))) _Float16 half8;
typedef __attribute__((ext_vector_type(4))) _Float16 h16x4;
typedef __attribute__((ext_vector_type(4))) float f32x4;

__device__ __forceinline__ half8 hmax8(half8 a, half8 b) {
    return __builtin_elementwise_max(a, b);   // v_pk_max_f16
}

// ---------------- CSR build (bucket-local; pairs packed src<<9 | dst&511) ----------------

__global__ void kbcnt(const int* __restrict__ ei, int E, int* __restrict__ gcnt) {
    __shared__ int h[256];
    int t = threadIdx.x;
    h[t] = 0;
    __syncthreads();
    for (int e = blockIdx.x * 256 + t; e < E; e += gridDim.x * 256)
        atomicAdd(&h[ei[E + e] >> 9], 1);
    __syncthreads();
    if (h[t]) atomicAdd(&gcnt[t], h[t]);
}

__global__ void kbscan(const int* __restrict__ gcnt, int* __restrict__ gbs,
                       int* __restrict__ gbc, int NB, int E,
                       int* __restrict__ rs, int N) {
    __shared__ int sm[256];
    int t = threadIdx.x;
    int v = (t < NB) ? gcnt[t] : 0;
    sm[t] = v;
    __syncthreads();
    for (int off = 1; off < 256; off <<= 1) {
        int add = (t >= off) ? sm[t - off] : 0;
        __syncthreads();
        sm[t] += add;
        __syncthreads();
    }
    int excl = sm[t] - v;
    if (t < NB) { gbs[t] = excl; gbc[t] = excl; }
    if (t == NB - 1) gbs[NB] = excl + v;    // == E
    if (t == 0) rs[N] = E;
}

__global__ void kbin(const int* __restrict__ ei, int E,
                     int* __restrict__ gbc, int* __restrict__ pairs, int NB) {
    __shared__ int hist[256];
    __shared__ int basep[256];
    const int t = threadIdx.x;
    const int c0 = blockIdx.x * 4096;
    hist[t] = 0;
    __syncthreads();
    int s[16], d[16];
#pragma unroll
    for (int i = 0; i < 16; ++i) {
        int e = c0 + i * 256 + t;
        if (e < E) {
            s[i] = ei[e];
            d[i] = ei[E + e];
            atomicAdd(&hist[d[i] >> 9], 1);
        } else d[i] = -1;
    }
    __syncthreads();
    if (t < NB) {
        basep[t] = atomicAdd(&gbc[t], hist[t]);
        hist[t] = 0;
    }
    __syncthreads();
#pragma unroll
    for (int i = 0; i < 16; ++i) {
        if (d[i] >= 0) {
            int b = d[i] >> 9;
            int off = atomicAdd(&hist[b], 1);
            pairs[basep[b] + off] = (s[i] << 9) | (d[i] & 511);
        }
    }
}

// ssrc stores BYTE offsets (src * 128) for the fp16 row gather.
__global__ void __launch_bounds__(256) kfinal(
        const int* __restrict__ pairs, const int* __restrict__ gbs,
        int* __restrict__ rs, int* __restrict__ ssrc, int N) {
    __shared__ int lcnt[512];
    __shared__ int lcur[512];
    __shared__ int ps[256];
    const int b = blockIdx.x;
    const int t = threadIdx.x;
    const int n0 = b << 9;
    const int e0 = gbs[b], e1 = gbs[b + 1];
    lcnt[t] = 0;
    lcnt[t + 256] = 0;
    __syncthreads();
    for (int e = e0 + t; e < e1; e += 256)
        atomicAdd(&lcnt[pairs[e] & 511], 1);
    __syncthreads();
    int c0 = lcnt[2 * t], c1 = lcnt[2 * t + 1];
    int sum = c0 + c1;
    ps[t] = sum;
    __syncthreads();
    for (int off = 1; off < 256; off <<= 1) {
        int add = (t >= off) ? ps[t - off] : 0;
        __syncthreads();
        ps[t] += add;
        __syncthreads();
    }
    int excl = ps[t] - sum;
    lcur[2 * t] = excl;
    lcur[2 * t + 1] = excl + c0;
    int n = n0 + 2 * t;
    if (n < N) rs[n] = e0 + excl;
    if (n + 1 < N) rs[n + 1] = e0 + excl + c0;
    __syncthreads();
    for (int e = e0 + t; e < e1; e += 256) {
        int p = pairs[e];
        int pos = atomicAdd(&lcur[p & 511], 1);
        ssrc[e0 + pos] = (int)((unsigned)p >> 9) << 7;   // byte offset of fp16 row
    }
}

// ---------------- fp32 x -> fp16 plane ----------------

__global__ void kcvt(const float* __restrict__ x, half_t* __restrict__ phi, int n4) {
    int i = blockIdx.x * blockDim.x + threadIdx.x;
    if (i < n4) {
        f32x4 v = ((const f32x4*)x)[i];
        h16x4 hi;
#pragma unroll
        for (int c = 0; c < 4; ++c) hi[c] = (half_t)v[c];
        ((h16x4*)phi)[i] = hi;
    }
}

// ---------------- weight prep: fp16 hi/lo MFMA B-fragments ----------------
// B[k][j], k in [0,128): k<64 -> Wl[j][k]; k>=64 -> Wr[j][k-64]
// frag f = (s*4+t)*2 (+1 for lo); element [lane][i]: k = s*32+(lane>>4)*8+i, j = t*16+(lane&15)

__global__ void kprepw(const float* __restrict__ Wl, const float* __restrict__ Wr,
                       half_t* __restrict__ Bf) {
    int id = blockIdx.x * blockDim.x + threadIdx.x;
    if (id >= 6 * 4 * 4 * 64 * 8) return;
    int i = id & 7;
    int lane = (id >> 3) & 63;
    int t = (id >> 9) & 3;
    int s = (id >> 11) & 3;
    int layer = id >> 13;
    int k = s * 32 + (lane >> 4) * 8 + i;
    int j = t * 16 + (lane & 15);
    float v = (k < 64) ? Wl[(layer * 64 + j) * 64 + k]
                       : Wr[(layer * 64 + j) * 64 + (k - 64)];
    half_t hi = (half_t)v;
    half_t lo = (half_t)(v - (float)hi);
    int f = (s * 4 + t) * 2;
    int base = layer * 16384 + f * 512 + lane * 8 + i;
    Bf[base] = hi;
    Bf[base + 512] = lo;
}

// ---------------- fused layer: GROUP-gather + in-wave LDS transpose + MFMA ----------------
// GATHER ACCESS PATTERN (the r6 fix): lane = (rgrp = lane>>2, sub = lane&3). The 4 lanes of
// rgrp walk row (m0+rgrp)'s edge list together (uniform trip count within the group); lane
// `sub` maxes bytes [sub*16,+16) and [64+sub*16,+16) of each source row. One wave64 load
// instruction = 16 rows x 64B CONTIGUOUS = 16 fully-used cache lines, vs the r5 layout's 64
// scattered 16B requests (25% line use) that saturated the L1 lookup pipe (r6: 73.8us/layer
// with hbm 20%, VALUBusy 12% -> address-issue-bound, not BW-bound).
// TRANSPOSE: wave-private LDS bounce (no barrier; same-wave DS ops are ordered) moves
// (rgrp,sub) -> A-frag (lrow,quad) layout. Row stride 144B keeps ds_read_b128 at the 8-phase
// floor. Root rows m0..m0+15 are consecutive -> direct loads already coalesce.
// REGISTER BUDGET (r3/r4): MFMA kernels split the wave budget evenly arch/AGPR;
// (256,3) -> 84 arch VGPRs. Loop live set ~55 -> no spill. 3 blocks/CU, 41KB LDS.

__global__ void __launch_bounds__(256, 3) kfused(
        const half_t* __restrict__ hin, const int* __restrict__ rs,
        const int* __restrict__ soff, const half_t* __restrict__ Bf,
        const float* __restrict__ bias, float* __restrict__ out32,
        half_t* __restrict__ hout, int N, int last) {
    __shared__ half_t Bs[16384];                      // 32 KB: 32 frags x 512 halfs
    __shared__ __align__(16) half_t Tr[4 * 16 * 72];  // 9 KB: per-wave 16 rows x 144B
    const int tid = threadIdx.x;
    const int lane = tid & 63;
    const int wid = tid >> 6;
    const int quad = lane >> 4;
    const int lrow = lane & 15;
    const int rgrp = lane >> 2;                       // row owned by this 4-lane group
    const int sub = lane & 3;                         // 16B slice within 64B half-row
    const int wv = (blockIdx.x * blockDim.x + tid) >> 6;
    const int nwv = (gridDim.x * blockDim.x) >> 6;
    const int ntiles = (N + 15) >> 4;

    // stage weights: 2048 half8 elements, 8 per thread, coalesced
    {
        const half8* __restrict__ Bg = (const half8*)Bf;
        half8* Bsh = (half8*)Bs;
#pragma unroll
        for (int i = 0; i < 8; ++i)
            Bsh[i * 256 + tid] = Bg[i * 256 + tid];
    }
    __syncthreads();
    const half8* __restrict__ Bls = (const half8*)Bs;
    half_t* tw = &Tr[wid * 1152];                     // wave-private transpose buffer

    const char* hb0 = (const char*)hin + sub * 16;        // + soff[e]: bytes [sub*16,+16)
    const char* hb1 = (const char*)hin + 64 + sub * 16;   // + soff[e]: bytes [64+sub*16,+16)
    const half_t NEG = (half_t)(-65504.0f);

    for (int tile = wv; tile < ntiles; tile += nwv) {
        const int m0 = tile << 4;

        // ---- group gather: 4 lanes share row m0+rgrp, uniform edge loop ----
        int grow = m0 + rgrp;
        if (grow >= N) grow = N - 1;
        int beg = rs[grow], end = rs[grow + 1];
        int lastE = end - 1;
        half8 macc0 = {NEG, NEG, NEG, NEG, NEG, NEG, NEG, NEG};
        half8 macc1 = macc0;
        for (int e = beg; e < end; e += 2) {   // clamped unroll-2: re-max of seen edge is no-op
            int e1 = (e + 1 <= lastE) ? e + 1 : lastE;
            int o0 = soff[e], o1 = soff[e1];
            macc0 = hmax8(macc0, *(const half8*)(hb0 + o0));
            macc1 = hmax8(macc1, *(const half8*)(hb1 + o0));
            macc0 = hmax8(macc0, *(const half8*)(hb0 + o1));
            macc1 = hmax8(macc1, *(const half8*)(hb1 + o1));
        }
        if (end <= beg) {                      // no in-edges -> 0 (PyG convention)
            half8 z = {(half_t)0.f, (half_t)0.f, (half_t)0.f, (half_t)0.f,
                       (half_t)0.f, (half_t)0.f, (half_t)0.f, (half_t)0.f};
            macc0 = z; macc1 = z;
        }

        // ---- in-wave transpose (rgrp,sub) -> (lrow,quad); no barrier needed ----
        *(half8*)(tw + rgrp * 72 + sub * 8)      = macc0;
        *(half8*)(tw + rgrp * 72 + 32 + sub * 8) = macc1;
        half8 Aa0 = *(const half8*)(tw + lrow * 72 + quad * 8);
        half8 Aa1 = *(const half8*)(tw + lrow * 72 + 32 + quad * 8);

        // ---- root features: rows m0..m0+15 contiguous -> direct loads coalesce ----
        int row = m0 + lrow;
        if (row >= N) row = N - 1;
        const char* ph = (const char*)hin + (size_t)row * 128 + quad * 16;
        half8 Hh0 = *(const half8*)(ph);
        half8 Hh1 = *(const half8*)(ph + 64);

        f32x4 acc[4] = {{0.f, 0.f, 0.f, 0.f}, {0.f, 0.f, 0.f, 0.f},
                        {0.f, 0.f, 0.f, 0.f}, {0.f, 0.f, 0.f, 0.f}};
#pragma unroll
        for (int t = 0; t < 4; ++t) {
            int f = t * 2;                      // (s*4+t)*2 for s=0..3 below
            acc[t] = __builtin_amdgcn_mfma_f32_16x16x32_f16(Aa0, Bls[(f     ) * 64 + lane],      acc[t], 0, 0, 0);
            acc[t] = __builtin_amdgcn_mfma_f32_16x16x32_f16(Aa0, Bls[(f     ) * 64 + 64 + lane], acc[t], 0, 0, 0);
            acc[t] = __builtin_amdgcn_mfma_f32_16x16x32_f16(Aa1, Bls[(f +  8) * 64 + lane],      acc[t], 0, 0, 0);
            acc[t] = __builtin_amdgcn_mfma_f32_16x16x32_f16(Aa1, Bls[(f +  8) * 64 + 64 + lane], acc[t], 0, 0, 0);
            acc[t] = __builtin_amdgcn_mfma_f32_16x16x32_f16(Hh0, Bls[(f + 16) * 64 + lane],      acc[t], 0, 0, 0);
            acc[t] = __builtin_amdgcn_mfma_f32_16x16x32_f16(Hh0, Bls[(f + 16) * 64 + 64 + lane], acc[t], 0, 0, 0);
            acc[t] = __builtin_amdgcn_mfma_f32_16x16x32_f16(Hh1, Bls[(f + 24) * 64 + lane],      acc[t], 0, 0, 0);
            acc[t] = __builtin_amdgcn_mfma_f32_16x16x32_f16(Hh1, Bls[(f + 24) * 64 + 64 + lane], acc[t], 0, 0, 0);
        }

        // C/D: col = t*16 + lrow, row = m0 + quad*4 + r
#pragma unroll
        for (int t = 0; t < 4; ++t) {
            int col = t * 16 + lrow;
            float bsv = bias[t * 16 + lrow];
#pragma unroll
            for (int r = 0; r < 4; ++r) {
                int orow = m0 + quad * 4 + r;
                if (orow < N) {
                    float v = acc[t][r] + bsv;
                    if (!last) {
                        v = fmaxf(v, 0.0f);
                        hout[(size_t)orow * DIM + col] = (half_t)v;
                    } else {
                        out32[(size_t)orow * DIM + col] = v;
                    }
                }
            }
        }
    }
}

// ---------------- host ----------------

extern "C" void kernel_launch(void* const* d_in, const int* in_sizes, int n_in,
                              void* d_out, int out_size, void* d_ws, size_t ws_size,
                              hipStream_t stream) {
    const float* x  = (const float*)d_in[0];
    const int*   ei = (const int*)d_in[1];
    const float* Wl = (const float*)d_in[2];
    const float* bl = (const float*)d_in[3];
    const float* Wr = (const float*)d_in[4];
    int N = in_sizes[0] / DIM;
    int E = in_sizes[1] / 2;

    size_t nd = (size_t)N * DIM;
    half_t* p0    = (half_t*)d_ws;           // fp16 h ping
    half_t* p1    = p0 + nd;                 // fp16 h pong
    half_t* scratch = p1 + nd;               // nd halfs; holds `pairs` during CSR build
    int*    rs    = (int*)(scratch + nd);    // N+1 used, N+4 reserved
    int*    ssrc  = rs + (N + 4);            // byte offsets
    int*    gcnt  = ssrc + E;                // 256
    int*    gbs   = gcnt + 256;              // NB+1 (260 reserved)
    int*    gbc   = gbs + 260;               // 256
    half_t* Bf    = (half_t*)(gbc + 256);    // 6 layers * 16384 halfs

    int NB = (N + 511) >> 9;                 // 196 for N=100000
    int* pairs = (int*)scratch;

    hipMemsetAsync(gcnt, 0, 256 * sizeof(int), stream);
    kbcnt<<<640, 256, 0, stream>>>(ei, E, gcnt);
    kbscan<<<1, 256, 0, stream>>>(gcnt, gbs, gbc, NB, E, rs, N);
    kbin<<<(E + 4095) / 4096, 256, 0, stream>>>(ei, E, gbc, pairs, NB);
    kfinal<<<NB, 256, 0, stream>>>(pairs, gbs, rs, ssrc, N);
    kprepw<<<(6 * 4 * 4 * 64 * 8 + 255) / 256, 256, 0, stream>>>(Wl, Wr, Bf);
    kcvt<<<((int)(nd / 4) + 255) / 256, 256, 0, stream>>>(x, p0, (int)(nd / 4));

    int ntiles = (N + 15) >> 4;
    int gblocks = (ntiles + 3) >> 2;         // ~1 tile per wave; queued blocks backfill
    for (int l = 0; l < 6; ++l) {
        half_t* ih = (l & 1) ? p1 : p0;
        half_t* oh = (l & 1) ? p0 : p1;
        int last = (l == 5);
        kfused<<<gblocks, 256, 0, stream>>>(ih, rs, ssrc, Bf + l * 16384, bl + l * 64,
                                            (float*)d_out, oh, N, last);
    }
}

// Round 10
// 521.505 us; speedup vs baseline: 1.3559x; 1.0865x over previous
//
#include <hip/hip_runtime.h>
#include <hip/hip_bf16.h>
#include <math.h>

#define DIM 64

typedef _Float16 half_t;
typedef __attribute__((ext_vector_type(8))) _Float16 half8;
typedef __attribute__((ext_vector_type(4))) _Float16 h16x4;
typedef __attribute__((ext_vector_type(4))) float f32x4;

__device__ __forceinline__ half8 hmax8(half8 a, half8 b) {
    return __builtin_elementwise_max(a, b);   // v_pk_max_f16
}

// ---------------- CSR build (bucket-local; pairs packed src<<9 | dst&511) ----------------

__global__ void kbcnt(const int* __restrict__ ei, int E, int* __restrict__ gcnt) {
    __shared__ int h[256];
    int t = threadIdx.x;
    h[t] = 0;
    __syncthreads();
    for (int e = blockIdx.x * 256 + t; e < E; e += gridDim.x * 256)
        atomicAdd(&h[ei[E + e] >> 9], 1);
    __syncthreads();
    if (h[t]) atomicAdd(&gcnt[t], h[t]);
}

__global__ void kbscan(const int* __restrict__ gcnt, int* __restrict__ gbs,
                       int* __restrict__ gbc, int NB, int E,
                       int* __restrict__ rs, int N) {
    __shared__ int sm[256];
    int t = threadIdx.x;
    int v = (t < NB) ? gcnt[t] : 0;
    sm[t] = v;
    __syncthreads();
    for (int off = 1; off < 256; off <<= 1) {
        int add = (t >= off) ? sm[t - off] : 0;
        __syncthreads();
        sm[t] += add;
        __syncthreads();
    }
    int excl = sm[t] - v;
    if (t < NB) { gbs[t] = excl; gbc[t] = excl; }
    if (t == NB - 1) gbs[NB] = excl + v;    // == E
    if (t == 0) rs[N] = E;
}

__global__ void kbin(const int* __restrict__ ei, int E,
                     int* __restrict__ gbc, int* __restrict__ pairs, int NB) {
    __shared__ int hist[256];
    __shared__ int basep[256];
    const int t = threadIdx.x;
    const int c0 = blockIdx.x * 4096;
    hist[t] = 0;
    __syncthreads();
    int s[16], d[16];
#pragma unroll
    for (int i = 0; i < 16; ++i) {
        int e = c0 + i * 256 + t;
        if (e < E) {
            s[i] = ei[e];
            d[i] = ei[E + e];
            atomicAdd(&hist[d[i] >> 9], 1);
        } else d[i] = -1;
    }
    __syncthreads();
    if (t < NB) {
        basep[t] = atomicAdd(&gbc[t], hist[t]);
        hist[t] = 0;
    }
    __syncthreads();
#pragma unroll
    for (int i = 0; i < 16; ++i) {
        if (d[i] >= 0) {
            int b = d[i] >> 9;
            int off = atomicAdd(&hist[b], 1);
            pairs[basep[b] + off] = (s[i] << 9) | (d[i] & 511);
        }
    }
}

// ssrc stores BYTE offsets (src * 128) for the fp16 row gather.
__global__ void __launch_bounds__(256) kfinal(
        const int* __restrict__ pairs, const int* __restrict__ gbs,
        int* __restrict__ rs, int* __restrict__ ssrc, int N) {
    __shared__ int lcnt[512];
    __shared__ int lcur[512];
    __shared__ int ps[256];
    const int b = blockIdx.x;
    const int t = threadIdx.x;
    const int n0 = b << 9;
    const int e0 = gbs[b], e1 = gbs[b + 1];
    lcnt[t] = 0;
    lcnt[t + 256] = 0;
    __syncthreads();
    for (int e = e0 + t; e < e1; e += 256)
        atomicAdd(&lcnt[pairs[e] & 511], 1);
    __syncthreads();
    int c0 = lcnt[2 * t], c1 = lcnt[2 * t + 1];
    int sum = c0 + c1;
    ps[t] = sum;
    __syncthreads();
    for (int off = 1; off < 256; off <<= 1) {
        int add = (t >= off) ? ps[t - off] : 0;
        __syncthreads();
        ps[t] += add;
        __syncthreads();
    }
    int excl = ps[t] - sum;
    lcur[2 * t] = excl;
    lcur[2 * t + 1] = excl + c0;
    int n = n0 + 2 * t;
    if (n < N) rs[n] = e0 + excl;
    if (n + 1 < N) rs[n + 1] = e0 + excl + c0;
    __syncthreads();
    for (int e = e0 + t; e < e1; e += 256) {
        int p = pairs[e];
        int pos = atomicAdd(&lcur[p & 511], 1);
        ssrc[e0 + pos] = (int)((unsigned)p >> 9) << 7;   // byte offset of fp16 row
    }
}

// ---------------- fp32 x -> fp16 plane ----------------

__global__ void kcvt(const float* __restrict__ x, half_t* __restrict__ phi, int n4) {
    int i = blockIdx.x * blockDim.x + threadIdx.x;
    if (i < n4) {
        f32x4 v = ((const f32x4*)x)[i];
        h16x4 hi;
#pragma unroll
        for (int c = 0; c < 4; ++c) hi[c] = (half_t)v[c];
        ((h16x4*)phi)[i] = hi;
    }
}

// ---------------- weight prep: fp16 hi/lo MFMA B-fragments ----------------
// B[k][j], k in [0,128): k<64 -> Wl[j][k]; k>=64 -> Wr[j][k-64]
// frag f = (s*4+t)*2 (+1 for lo); element [lane][i]: k = s*32+(lane>>4)*8+i, j = t*16+(lane&15)

__global__ void kprepw(const float* __restrict__ Wl, const float* __restrict__ Wr,
                       half_t* __restrict__ Bf) {
    int id = blockIdx.x * blockDim.x + threadIdx.x;
    if (id >= 6 * 4 * 4 * 64 * 8) return;
    int i = id & 7;
    int lane = (id >> 3) & 63;
    int t = (id >> 9) & 3;
    int s = (id >> 11) & 3;
    int layer = id >> 13;
    int k = s * 32 + (lane >> 4) * 8 + i;
    int j = t * 16 + (lane & 15);
    float v = (k < 64) ? Wl[(layer * 64 + j) * 64 + k]
                       : Wr[(layer * 64 + j) * 64 + (k - 64)];
    half_t hi = (half_t)v;
    half_t lo = (half_t)(v - (float)hi);
    int f = (s * 4 + t) * 2;
    int base = layer * 16384 + f * 512 + lane * 8 + i;
    Bf[base] = hi;
    Bf[base + 512] = lo;
}

// ---------------- fused layer: 8-deep pipelined gather + LDS transpose + MFMA ----------------
// r7 POST-MORTEM: both 16B/lane and 64B/group gathers ran ~72us/layer with all counters idle
// -> the cost is the per-iteration LATENCY CHAIN (soff -> wait -> gather -> wait -> hmax),
// one full memory latency per 2 edges, and at 2-3 waves/SIMD (MFMA reg pressure) TLP can't
// cover it. THE FIX: 8 edges in flight per latency. Layout: sub8 = lane&7 owns one 16B slice
// of the 128B row; r8 = lane>>3 owns row (m0 + pass*8 + r8); 2 sub-passes cover the 16-row
// tile. Each iteration issues 8 independent edge-gathers (1 half8/lane each = 32 VGPRs in
// flight), then prefetches the NEXT 8 soff offsets (issued after the gathers, so consuming
// the gathers waits vmcnt(8) and leaves the prefetch in flight), then tree-folds.
// Period ~= one latency per 8 edges instead of per 2.
// REGISTER BUDGET (r3/r4): MFMA kernels split the wave budget evenly arch/AGPR;
// (256,3) -> 84 arch VGPRs. Loop peak ~70 (8 off + 8 pref + 32 data + 8 acc + addr) -> fits.
// Transpose bounce: wave-private, 144B row stride (16B-aligned, 2-way bank alias = free).

__global__ void __launch_bounds__(256, 3) kfused(
        const half_t* __restrict__ hin, const int* __restrict__ rs,
        const int* __restrict__ soff, const half_t* __restrict__ Bf,
        const float* __restrict__ bias, float* __restrict__ out32,
        half_t* __restrict__ hout, int N, int last) {
    __shared__ half_t Bs[16384];                      // 32 KB: 32 frags x 512 halfs
    __shared__ __align__(16) half_t Tr[4 * 16 * 72];  // 9 KB: per-wave 16 rows x 144B
    const int tid = threadIdx.x;
    const int lane = tid & 63;
    const int wid = tid >> 6;
    const int quad = lane >> 4;
    const int lrow = lane & 15;
    const int r8 = lane >> 3;                         // row within sub-pass (0..7)
    const int sub8 = lane & 7;                        // 16B slice of the 128B row
    const int wv = (blockIdx.x * blockDim.x + tid) >> 6;
    const int nwv = (gridDim.x * blockDim.x) >> 6;
    const int ntiles = (N + 15) >> 4;

    // stage weights: 2048 half8 elements, 8 per thread, coalesced
    {
        const half8* __restrict__ Bg = (const half8*)Bf;
        half8* Bsh = (half8*)Bs;
#pragma unroll
        for (int i = 0; i < 8; ++i)
            Bsh[i * 256 + tid] = Bg[i * 256 + tid];
    }
    __syncthreads();
    const half8* __restrict__ Bls = (const half8*)Bs;
    half_t* tw = &Tr[wid * 1152];                     // wave-private transpose buffer

    const char* hb = (const char*)hin + sub8 * 16;    // + soff[e] = src*128 + sub8*16
    const half_t NEG = (half_t)(-65504.0f);

    for (int tile = wv; tile < ntiles; tile += nwv) {
        const int m0 = tile << 4;

        // ---- gather: 2 sub-passes x 8 rows; 8-lane group shares a row; 8 edges/iteration ----
#pragma unroll
        for (int p = 0; p < 2; ++p) {
            int grow = m0 + p * 8 + r8;
            if (grow >= N) grow = N - 1;
            int beg = rs[grow], end = rs[grow + 1];
            int lastE = end - 1;
            half8 a0 = {NEG, NEG, NEG, NEG, NEG, NEG, NEG, NEG};
            half8 a1 = a0;
            if (end > beg) {
                // prologue: first 8 offsets (clamped; re-max of a seen edge is a no-op)
                int o0 = soff[beg];
                int o1 = soff[(beg + 1 <= lastE) ? beg + 1 : lastE];
                int o2 = soff[(beg + 2 <= lastE) ? beg + 2 : lastE];
                int o3 = soff[(beg + 3 <= lastE) ? beg + 3 : lastE];
                int o4 = soff[(beg + 4 <= lastE) ? beg + 4 : lastE];
                int o5 = soff[(beg + 5 <= lastE) ? beg + 5 : lastE];
                int o6 = soff[(beg + 6 <= lastE) ? beg + 6 : lastE];
                int o7 = soff[(beg + 7 <= lastE) ? beg + 7 : lastE];
                for (int e = beg; e < end; e += 8) {
                    // issue 8 independent gathers
                    half8 g0 = *(const half8*)(hb + o0);
                    half8 g1 = *(const half8*)(hb + o1);
                    half8 g2 = *(const half8*)(hb + o2);
                    half8 g3 = *(const half8*)(hb + o3);
                    half8 g4 = *(const half8*)(hb + o4);
                    half8 g5 = *(const half8*)(hb + o5);
                    half8 g6 = *(const half8*)(hb + o6);
                    half8 g7 = *(const half8*)(hb + o7);
                    // prefetch next iteration's offsets (clamped; harmless on final iter)
                    int ne = e + 8;
                    int q0 = soff[(ne     <= lastE) ? ne     : lastE];
                    int q1 = soff[(ne + 1 <= lastE) ? ne + 1 : lastE];
                    int q2 = soff[(ne + 2 <= lastE) ? ne + 2 : lastE];
                    int q3 = soff[(ne + 3 <= lastE) ? ne + 3 : lastE];
                    int q4 = soff[(ne + 4 <= lastE) ? ne + 4 : lastE];
                    int q5 = soff[(ne + 5 <= lastE) ? ne + 5 : lastE];
                    int q6 = soff[(ne + 6 <= lastE) ? ne + 6 : lastE];
                    int q7 = soff[(ne + 7 <= lastE) ? ne + 7 : lastE];
                    // tree-fold (consumes gathers; prefetches stay in flight)
                    a0 = hmax8(a0, hmax8(hmax8(g0, g1), hmax8(g2, g3)));
                    a1 = hmax8(a1, hmax8(hmax8(g4, g5), hmax8(g6, g7)));
                    o0 = q0; o1 = q1; o2 = q2; o3 = q3;
                    o4 = q4; o5 = q5; o6 = q6; o7 = q7;
                }
                a0 = hmax8(a0, a1);
            } else {
                half8 z = {(half_t)0.f, (half_t)0.f, (half_t)0.f, (half_t)0.f,
                           (half_t)0.f, (half_t)0.f, (half_t)0.f, (half_t)0.f};
                a0 = z;                          // no in-edges -> 0 (PyG convention)
            }
            // transpose write: row (p*8+r8), slice sub8 (wave-private; same-wave DS ordered)
            *(half8*)(tw + (p * 8 + r8) * 72 + sub8 * 8) = a0;
        }

        // ---- read A-frags (lrow, quad) from transpose buffer ----
        half8 Aa0 = *(const half8*)(tw + lrow * 72 + quad * 8);
        half8 Aa1 = *(const half8*)(tw + lrow * 72 + 32 + quad * 8);

        // ---- root features: rows m0..m0+15 contiguous -> direct loads coalesce ----
        int row = m0 + lrow;
        if (row >= N) row = N - 1;
        const char* ph = (const char*)hin + (size_t)row * 128 + quad * 16;
        half8 Hh0 = *(const half8*)(ph);
        half8 Hh1 = *(const half8*)(ph + 64);

        f32x4 acc[4] = {{0.f, 0.f, 0.f, 0.f}, {0.f, 0.f, 0.f, 0.f},
                        {0.f, 0.f, 0.f, 0.f}, {0.f, 0.f, 0.f, 0.f}};
#pragma unroll
        for (int t = 0; t < 4; ++t) {
            int f = t * 2;                      // (s*4+t)*2 for s=0..3 below
            acc[t] = __builtin_amdgcn_mfma_f32_16x16x32_f16(Aa0, Bls[(f     ) * 64 + lane],      acc[t], 0, 0, 0);
            acc[t] = __builtin_amdgcn_mfma_f32_16x16x32_f16(Aa0, Bls[(f     ) * 64 + 64 + lane], acc[t], 0, 0, 0);
            acc[t] = __builtin_amdgcn_mfma_f32_16x16x32_f16(Aa1, Bls[(f +  8) * 64 + lane],      acc[t], 0, 0, 0);
            acc[t] = __builtin_amdgcn_mfma_f32_16x16x32_f16(Aa1, Bls[(f +  8) * 64 + 64 + lane], acc[t], 0, 0, 0);
            acc[t] = __builtin_amdgcn_mfma_f32_16x16x32_f16(Hh0, Bls[(f + 16) * 64 + lane],      acc[t], 0, 0, 0);
            acc[t] = __builtin_amdgcn_mfma_f32_16x16x32_f16(Hh0, Bls[(f + 16) * 64 + 64 + lane], acc[t], 0, 0, 0);
            acc[t] = __builtin_amdgcn_mfma_f32_16x16x32_f16(Hh1, Bls[(f + 24) * 64 + lane],      acc[t], 0, 0, 0);
            acc[t] = __builtin_amdgcn_mfma_f32_16x16x32_f16(Hh1, Bls[(f + 24) * 64 + 64 + lane], acc[t], 0, 0, 0);
        }

        // C/D: col = t*16 + lrow, row = m0 + quad*4 + r
#pragma unroll
        for (int t = 0; t < 4; ++t) {
            int col = t * 16 + lrow;
            float bsv = bias[t * 16 + lrow];
#pragma unroll
            for (int r = 0; r < 4; ++r) {
                int orow = m0 + quad * 4 + r;
                if (orow < N) {
                    float v = acc[t][r] + bsv;
                    if (!last) {
                        v = fmaxf(v, 0.0f);
                        hout[(size_t)orow * DIM + col] = (half_t)v;
                    } else {
                        out32[(size_t)orow * DIM + col] = v;
                    }
                }
            }
        }
    }
}

// ---------------- host ----------------

extern "C" void kernel_launch(void* const* d_in, const int* in_sizes, int n_in,
                              void* d_out, int out_size, void* d_ws, size_t ws_size,
                              hipStream_t stream) {
    const float* x  = (const float*)d_in[0];
    const int*   ei = (const int*)d_in[1];
    const float* Wl = (const float*)d_in[2];
    const float* bl = (const float*)d_in[3];
    const float* Wr = (const float*)d_in[4];
    int N = in_sizes[0] / DIM;
    int E = in_sizes[1] / 2;

    size_t nd = (size_t)N * DIM;
    half_t* p0    = (half_t*)d_ws;           // fp16 h ping
    half_t* p1    = p0 + nd;                 // fp16 h pong
    half_t* scratch = p1 + nd;               // nd halfs; holds `pairs` during CSR build
    int*    rs    = (int*)(scratch + nd);    // N+1 used, N+4 reserved
    int*    ssrc  = rs + (N + 4);            // byte offsets
    int*    gcnt  = ssrc + E;                // 256
    int*    gbs   = gcnt + 256;              // NB+1 (260 reserved)
    int*    gbc   = gbs + 260;               // 256
    half_t* Bf    = (half_t*)(gbc + 256);    // 6 layers * 16384 halfs

    int NB = (N + 511) >> 9;                 // 196 for N=100000
    int* pairs = (int*)scratch;

    hipMemsetAsync(gcnt, 0, 256 * sizeof(int), stream);
    kbcnt<<<640, 256, 0, stream>>>(ei, E, gcnt);
    kbscan<<<1, 256, 0, stream>>>(gcnt, gbs, gbc, NB, E, rs, N);
    kbin<<<(E + 4095) / 4096, 256, 0, stream>>>(ei, E, gbc, pairs, NB);
    kfinal<<<NB, 256, 0, stream>>>(pairs, gbs, rs, ssrc, N);
    kprepw<<<(6 * 4 * 4 * 64 * 8 + 255) / 256, 256, 0, stream>>>(Wl, Wr, Bf);
    kcvt<<<((int)(nd / 4) + 255) / 256, 256, 0, stream>>>(x, p0, (int)(nd / 4));

    int ntiles = (N + 15) >> 4;
    int gblocks = (ntiles + 3) >> 2;         // ~1 tile per wave; queued blocks backfill
    for (int l = 0; l < 6; ++l) {
        half_t* ih = (l & 1) ? p1 : p0;
        half_t* oh = (l & 1) ? p0 : p1;
        int last = (l == 5);
        kfused<<<gblocks, 256, 0, stream>>>(ih, rs, ssrc, Bf + l * 16384, bl + l * 64,
                                            (float*)d_out, oh, N, last);
    }
}

// Round 11
// 475.021 us; speedup vs baseline: 1.4886x; 1.0979x over previous
//
#include <hip/hip_runtime.h>
#include <hip/hip_bf16.h>
#include <math.h>

#define DIM 64

typedef _Float16 half_t;
typedef __attribute__((ext_vector_type(8))) _Float16 half8;
typedef __attribute__((ext_vector_type(4))) _Float16 h16x4;
typedef __attribute__((ext_vector_type(4))) float f32x4;

__device__ __forceinline__ half8 hmax8(half8 a, half8 b) {
    return __builtin_elementwise_max(a, b);   // v_pk_max_f16
}

// ---------------- CSR build (bucket-local; pairs packed src<<9 | dst&511) ----------------

__global__ void kbcnt(const int* __restrict__ ei, int E, int* __restrict__ gcnt) {
    __shared__ int h[256];
    int t = threadIdx.x;
    h[t] = 0;
    __syncthreads();
    for (int e = blockIdx.x * 256 + t; e < E; e += gridDim.x * 256)
        atomicAdd(&h[ei[E + e] >> 9], 1);
    __syncthreads();
    if (h[t]) atomicAdd(&gcnt[t], h[t]);
}

__global__ void kbscan(const int* __restrict__ gcnt, int* __restrict__ gbs,
                       int* __restrict__ gbc, int NB, int E,
                       int* __restrict__ rs, int N) {
    __shared__ int sm[256];
    int t = threadIdx.x;
    int v = (t < NB) ? gcnt[t] : 0;
    sm[t] = v;
    __syncthreads();
    for (int off = 1; off < 256; off <<= 1) {
        int add = (t >= off) ? sm[t - off] : 0;
        __syncthreads();
        sm[t] += add;
        __syncthreads();
    }
    int excl = sm[t] - v;
    if (t < NB) { gbs[t] = excl; gbc[t] = excl; }
    if (t == NB - 1) gbs[NB] = excl + v;    // == E
    if (t == 0) rs[N] = E;
}

__global__ void kbin(const int* __restrict__ ei, int E,
                     int* __restrict__ gbc, int* __restrict__ pairs, int NB) {
    __shared__ int hist[256];
    __shared__ int basep[256];
    const int t = threadIdx.x;
    const int c0 = blockIdx.x * 4096;
    hist[t] = 0;
    __syncthreads();
    int s[16], d[16];
#pragma unroll
    for (int i = 0; i < 16; ++i) {
        int e = c0 + i * 256 + t;
        if (e < E) {
            s[i] = ei[e];
            d[i] = ei[E + e];
            atomicAdd(&hist[d[i] >> 9], 1);
        } else d[i] = -1;
    }
    __syncthreads();
    if (t < NB) {
        basep[t] = atomicAdd(&gbc[t], hist[t]);
        hist[t] = 0;
    }
    __syncthreads();
#pragma unroll
    for (int i = 0; i < 16; ++i) {
        if (d[i] >= 0) {
            int b = d[i] >> 9;
            int off = atomicAdd(&hist[b], 1);
            pairs[basep[b] + off] = (s[i] << 9) | (d[i] & 511);
        }
    }
}

// ssrc stores BYTE offsets (src * 128) for the fp16 row gather.
__global__ void __launch_bounds__(256) kfinal(
        const int* __restrict__ pairs, const int* __restrict__ gbs,
        int* __restrict__ rs, int* __restrict__ ssrc, int N) {
    __shared__ int lcnt[512];
    __shared__ int lcur[512];
    __shared__ int ps[256];
    const int b = blockIdx.x;
    const int t = threadIdx.x;
    const int n0 = b << 9;
    const int e0 = gbs[b], e1 = gbs[b + 1];
    lcnt[t] = 0;
    lcnt[t + 256] = 0;
    __syncthreads();
    for (int e = e0 + t; e < e1; e += 256)
        atomicAdd(&lcnt[pairs[e] & 511], 1);
    __syncthreads();
    int c0 = lcnt[2 * t], c1 = lcnt[2 * t + 1];
    int sum = c0 + c1;
    ps[t] = sum;
    __syncthreads();
    for (int off = 1; off < 256; off <<= 1) {
        int add = (t >= off) ? ps[t - off] : 0;
        __syncthreads();
        ps[t] += add;
        __syncthreads();
    }
    int excl = ps[t] - sum;
    lcur[2 * t] = excl;
    lcur[2 * t + 1] = excl + c0;
    int n = n0 + 2 * t;
    if (n < N) rs[n] = e0 + excl;
    if (n + 1 < N) rs[n + 1] = e0 + excl + c0;
    __syncthreads();
    for (int e = e0 + t; e < e1; e += 256) {
        int p = pairs[e];
        int pos = atomicAdd(&lcur[p & 511], 1);
        ssrc[e0 + pos] = (int)((unsigned)p >> 9) << 7;   // byte offset of fp16 row
    }
}

// ---------------- fp32 x -> fp16 plane ----------------

__global__ void kcvt(const float* __restrict__ x, half_t* __restrict__ phi, int n4) {
    int i = blockIdx.x * blockDim.x + threadIdx.x;
    if (i < n4) {
        f32x4 v = ((const f32x4*)x)[i];
        h16x4 hi;
#pragma unroll
        for (int c = 0; c < 4; ++c) hi[c] = (half_t)v[c];
        ((h16x4*)phi)[i] = hi;
    }
}

// ---------------- weight prep: fp16 hi/lo MFMA B-fragments ----------------
// B[k][j], k in [0,128): k<64 -> Wl[j][k]; k>=64 -> Wr[j][k-64]
// frag f = (s*4+t)*2 (+1 for lo); element [lane][i]: k = s*32+(lane>>4)*8+i, j = t*16+(lane&15)

__global__ void kprepw(const float* __restrict__ Wl, const float* __restrict__ Wr,
                       half_t* __restrict__ Bf) {
    int id = blockIdx.x * blockDim.x + threadIdx.x;
    if (id >= 6 * 4 * 4 * 64 * 8) return;
    int i = id & 7;
    int lane = (id >> 3) & 63;
    int t = (id >> 9) & 3;
    int s = (id >> 11) & 3;
    int layer = id >> 13;
    int k = s * 32 + (lane >> 4) * 8 + i;
    int j = t * 16 + (lane & 15);
    float v = (k < 64) ? Wl[(layer * 64 + j) * 64 + k]
                       : Wr[(layer * 64 + j) * 64 + (k - 64)];
    half_t hi = (half_t)v;
    half_t lo = (half_t)(v - (float)hi);
    int f = (s * 4 + t) * 2;
    int base = layer * 16384 + f * 512 + lane * 8 + i;
    Bf[base] = hi;
    Bf[base + 512] = lo;
}

// ---------------- fused layer: depth-4 pipelined gather + LDS transpose + MFMA ----------------
// r10 POST-MORTEM: depth-8 pipeline CONFIRMED the latency-chain theory (dur 71.8->64.2 even
// while spilling ~100MB of scratch: WRITE 25->79.7MB, FETCH 90->122MB). The 84-arch-reg half
// (MFMA even-split, r3/r4) can't hold 8 offsets + 8 prefetch + 32 data regs once the
// p-loop unroll lets the two sub-pass pipelines interleave. THIS ROUND: depth-4 (4 off +
// 4 pref + 16 data + 8 acc + ~20 addr ~= 52 regs, certain fit) and `#pragma unroll 1` on the
// p-loop so the sub-pass pipelines never coexist. Keeps ~half the chain reduction, reclaims
// the spill round-trip.
// Layout: sub8 = lane&7 owns one 16B slice of the 128B row; r8 = lane>>3 owns row
// (m0 + pass*8 + r8); 2 sub-passes cover the 16-row tile. Transpose bounce: wave-private,
// 144B row stride. REGISTER BUDGET (r3/r4): (256,3) -> 170/wave -> 84 arch VGPRs.

__global__ void __launch_bounds__(256, 3) kfused(
        const half_t* __restrict__ hin, const int* __restrict__ rs,
        const int* __restrict__ soff, const half_t* __restrict__ Bf,
        const float* __restrict__ bias, float* __restrict__ out32,
        half_t* __restrict__ hout, int N, int last) {
    __shared__ half_t Bs[16384];                      // 32 KB: 32 frags x 512 halfs
    __shared__ __align__(16) half_t Tr[4 * 16 * 72];  // 9 KB: per-wave 16 rows x 144B
    const int tid = threadIdx.x;
    const int lane = tid & 63;
    const int wid = tid >> 6;
    const int quad = lane >> 4;
    const int lrow = lane & 15;
    const int r8 = lane >> 3;                         // row within sub-pass (0..7)
    const int sub8 = lane & 7;                        // 16B slice of the 128B row
    const int wv = (blockIdx.x * blockDim.x + tid) >> 6;
    const int nwv = (gridDim.x * blockDim.x) >> 6;
    const int ntiles = (N + 15) >> 4;

    // stage weights: 2048 half8 elements, 8 per thread, coalesced
    {
        const half8* __restrict__ Bg = (const half8*)Bf;
        half8* Bsh = (half8*)Bs;
#pragma unroll
        for (int i = 0; i < 8; ++i)
            Bsh[i * 256 + tid] = Bg[i * 256 + tid];
    }
    __syncthreads();
    const half8* __restrict__ Bls = (const half8*)Bs;
    half_t* tw = &Tr[wid * 1152];                     // wave-private transpose buffer

    const char* hb = (const char*)hin + sub8 * 16;    // + soff[e] = src*128 + sub8*16
    const half_t NEG = (half_t)(-65504.0f);

    for (int tile = wv; tile < ntiles; tile += nwv) {
        const int m0 = tile << 4;

        // ---- gather: 2 sub-passes x 8 rows; 8-lane group shares a row; 4 edges/iteration ----
#pragma unroll 1
        for (int p = 0; p < 2; ++p) {
            int grow = m0 + p * 8 + r8;
            if (grow >= N) grow = N - 1;
            int beg = rs[grow], end = rs[grow + 1];
            int lastE = end - 1;
            half8 a0 = {NEG, NEG, NEG, NEG, NEG, NEG, NEG, NEG};
            half8 a1 = a0;
            if (end > beg) {
                // prologue: first 4 offsets (clamped; re-max of a seen edge is a no-op)
                int o0 = soff[beg];
                int o1 = soff[(beg + 1 <= lastE) ? beg + 1 : lastE];
                int o2 = soff[(beg + 2 <= lastE) ? beg + 2 : lastE];
                int o3 = soff[(beg + 3 <= lastE) ? beg + 3 : lastE];
                for (int e = beg; e < end; e += 4) {
                    // issue 4 independent gathers
                    half8 g0 = *(const half8*)(hb + o0);
                    half8 g1 = *(const half8*)(hb + o1);
                    half8 g2 = *(const half8*)(hb + o2);
                    half8 g3 = *(const half8*)(hb + o3);
                    // prefetch next iteration's offsets (clamped; harmless on final iter)
                    int ne = e + 4;
                    int q0 = soff[(ne     <= lastE) ? ne     : lastE];
                    int q1 = soff[(ne + 1 <= lastE) ? ne + 1 : lastE];
                    int q2 = soff[(ne + 2 <= lastE) ? ne + 2 : lastE];
                    int q3 = soff[(ne + 3 <= lastE) ? ne + 3 : lastE];
                    // tree-fold (consumes gathers; prefetches stay in flight)
                    a0 = hmax8(a0, hmax8(g0, g1));
                    a1 = hmax8(a1, hmax8(g2, g3));
                    o0 = q0; o1 = q1; o2 = q2; o3 = q3;
                }
                a0 = hmax8(a0, a1);
            } else {
                half8 z = {(half_t)0.f, (half_t)0.f, (half_t)0.f, (half_t)0.f,
                           (half_t)0.f, (half_t)0.f, (half_t)0.f, (half_t)0.f};
                a0 = z;                          // no in-edges -> 0 (PyG convention)
            }
            // transpose write: row (p*8+r8), slice sub8 (wave-private; same-wave DS ordered)
            *(half8*)(tw + (p * 8 + r8) * 72 + sub8 * 8) = a0;
        }

        // ---- read A-frags (lrow, quad) from transpose buffer ----
        half8 Aa0 = *(const half8*)(tw + lrow * 72 + quad * 8);
        half8 Aa1 = *(const half8*)(tw + lrow * 72 + 32 + quad * 8);

        // ---- root features: rows m0..m0+15 contiguous -> direct loads coalesce ----
        int row = m0 + lrow;
        if (row >= N) row = N - 1;
        const char* ph = (const char*)hin + (size_t)row * 128 + quad * 16;
        half8 Hh0 = *(const half8*)(ph);
        half8 Hh1 = *(const half8*)(ph + 64);

        f32x4 acc[4] = {{0.f, 0.f, 0.f, 0.f}, {0.f, 0.f, 0.f, 0.f},
                        {0.f, 0.f, 0.f, 0.f}, {0.f, 0.f, 0.f, 0.f}};
#pragma unroll
        for (int t = 0; t < 4; ++t) {
            int f = t * 2;                      // (s*4+t)*2 for s=0..3 below
            acc[t] = __builtin_amdgcn_mfma_f32_16x16x32_f16(Aa0, Bls[(f     ) * 64 + lane],      acc[t], 0, 0, 0);
            acc[t] = __builtin_amdgcn_mfma_f32_16x16x32_f16(Aa0, Bls[(f     ) * 64 + 64 + lane], acc[t], 0, 0, 0);
            acc[t] = __builtin_amdgcn_mfma_f32_16x16x32_f16(Aa1, Bls[(f +  8) * 64 + lane],      acc[t], 0, 0, 0);
            acc[t] = __builtin_amdgcn_mfma_f32_16x16x32_f16(Aa1, Bls[(f +  8) * 64 + 64 + lane], acc[t], 0, 0, 0);
            acc[t] = __builtin_amdgcn_mfma_f32_16x16x32_f16(Hh0, Bls[(f + 16) * 64 + lane],      acc[t], 0, 0, 0);
            acc[t] = __builtin_amdgcn_mfma_f32_16x16x32_f16(Hh0, Bls[(f + 16) * 64 + 64 + lane], acc[t], 0, 0, 0);
            acc[t] = __builtin_amdgcn_mfma_f32_16x16x32_f16(Hh1, Bls[(f + 24) * 64 + lane],      acc[t], 0, 0, 0);
            acc[t] = __builtin_amdgcn_mfma_f32_16x16x32_f16(Hh1, Bls[(f + 24) * 64 + 64 + lane], acc[t], 0, 0, 0);
        }

        // C/D: col = t*16 + lrow, row = m0 + quad*4 + r
#pragma unroll
        for (int t = 0; t < 4; ++t) {
            int col = t * 16 + lrow;
            float bsv = bias[t * 16 + lrow];
#pragma unroll
            for (int r = 0; r < 4; ++r) {
                int orow = m0 + quad * 4 + r;
                if (orow < N) {
                    float v = acc[t][r] + bsv;
                    if (!last) {
                        v = fmaxf(v, 0.0f);
                        hout[(size_t)orow * DIM + col] = (half_t)v;
                    } else {
                        out32[(size_t)orow * DIM + col] = v;
                    }
                }
            }
        }
    }
}

// ---------------- host ----------------

extern "C" void kernel_launch(void* const* d_in, const int* in_sizes, int n_in,
                              void* d_out, int out_size, void* d_ws, size_t ws_size,
                              hipStream_t stream) {
    const float* x  = (const float*)d_in[0];
    const int*   ei = (const int*)d_in[1];
    const float* Wl = (const float*)d_in[2];
    const float* bl = (const float*)d_in[3];
    const float* Wr = (const float*)d_in[4];
    int N = in_sizes[0] / DIM;
    int E = in_sizes[1] / 2;

    size_t nd = (size_t)N * DIM;
    half_t* p0    = (half_t*)d_ws;           // fp16 h ping
    half_t* p1    = p0 + nd;                 // fp16 h pong
    half_t* scratch = p1 + nd;               // nd halfs; holds `pairs` during CSR build
    int*    rs    = (int*)(scratch + nd);    // N+1 used, N+4 reserved
    int*    ssrc  = rs + (N + 4);            // byte offsets
    int*    gcnt  = ssrc + E;                // 256
    int*    gbs   = gcnt + 256;              // NB+1 (260 reserved)
    int*    gbc   = gbs + 260;               // 256
    half_t* Bf    = (half_t*)(gbc + 256);    // 6 layers * 16384 halfs

    int NB = (N + 511) >> 9;                 // 196 for N=100000
    int* pairs = (int*)scratch;

    hipMemsetAsync(gcnt, 0, 256 * sizeof(int), stream);
    kbcnt<<<640, 256, 0, stream>>>(ei, E, gcnt);
    kbscan<<<1, 256, 0, stream>>>(gcnt, gbs, gbc, NB, E, rs, N);
    kbin<<<(E + 4095) / 4096, 256, 0, stream>>>(ei, E, gbc, pairs, NB);
    kfinal<<<NB, 256, 0, stream>>>(pairs, gbs, rs, ssrc, N);
    kprepw<<<(6 * 4 * 4 * 64 * 8 + 255) / 256, 256, 0, stream>>>(Wl, Wr, Bf);
    kcvt<<<((int)(nd / 4) + 255) / 256, 256, 0, stream>>>(x, p0, (int)(nd / 4));

    int ntiles = (N + 15) >> 4;
    int gblocks = (ntiles + 3) >> 2;         // ~1 tile per wave; queued blocks backfill
    for (int l = 0; l < 6; ++l) {
        half_t* ih = (l & 1) ? p1 : p0;
        half_t* oh = (l & 1) ? p0 : p1;
        int last = (l == 5);
        kfused<<<gblocks, 256, 0, stream>>>(ih, rs, ssrc, Bf + l * 16384, bl + l * 64,
                                            (float*)d_out, oh, N, last);
    }
}

// Round 12
// 407.839 us; speedup vs baseline: 1.7338x; 1.1647x over previous
//
#include <hip/hip_runtime.h>
#include <hip/hip_bf16.h>
#include <math.h>

#define DIM 64

typedef _Float16 half_t;
typedef __attribute__((ext_vector_type(8))) _Float16 half8;
typedef __attribute__((ext_vector_type(4))) _Float16 h16x4;
typedef __attribute__((ext_vector_type(4))) float f32x4;

__device__ __forceinline__ half8 hmax8(half8 a, half8 b) {
    return __builtin_elementwise_max(a, b);   // v_pk_max_f16
}

// ---------------- CSR build (bucket-local; pairs packed src<<9 | dst&511) ----------------

__global__ void kbcnt(const int* __restrict__ ei, int E, int* __restrict__ gcnt) {
    __shared__ int h[256];
    int t = threadIdx.x;
    h[t] = 0;
    __syncthreads();
    for (int e = blockIdx.x * 256 + t; e < E; e += gridDim.x * 256)
        atomicAdd(&h[ei[E + e] >> 9], 1);
    __syncthreads();
    if (h[t]) atomicAdd(&gcnt[t], h[t]);
}

__global__ void kbscan(const int* __restrict__ gcnt, int* __restrict__ gbs,
                       int* __restrict__ gbc, int NB, int E,
                       int* __restrict__ rs, int N) {
    __shared__ int sm[256];
    int t = threadIdx.x;
    int v = (t < NB) ? gcnt[t] : 0;
    sm[t] = v;
    __syncthreads();
    for (int off = 1; off < 256; off <<= 1) {
        int add = (t >= off) ? sm[t - off] : 0;
        __syncthreads();
        sm[t] += add;
        __syncthreads();
    }
    int excl = sm[t] - v;
    if (t < NB) { gbs[t] = excl; gbc[t] = excl; }
    if (t == NB - 1) gbs[NB] = excl + v;    // == E
    if (t == 0) rs[N] = E;
}

__global__ void kbin(const int* __restrict__ ei, int E,
                     int* __restrict__ gbc, int* __restrict__ pairs, int NB) {
    __shared__ int hist[256];
    __shared__ int basep[256];
    const int t = threadIdx.x;
    const int c0 = blockIdx.x * 4096;
    hist[t] = 0;
    __syncthreads();
    int s[16], d[16];
#pragma unroll
    for (int i = 0; i < 16; ++i) {
        int e = c0 + i * 256 + t;
        if (e < E) {
            s[i] = ei[e];
            d[i] = ei[E + e];
            atomicAdd(&hist[d[i] >> 9], 1);
        } else d[i] = -1;
    }
    __syncthreads();
    if (t < NB) {
        basep[t] = atomicAdd(&gbc[t], hist[t]);
        hist[t] = 0;
    }
    __syncthreads();
#pragma unroll
    for (int i = 0; i < 16; ++i) {
        if (d[i] >= 0) {
            int b = d[i] >> 9;
            int off = atomicAdd(&hist[b], 1);
            pairs[basep[b] + off] = (s[i] << 9) | (d[i] & 511);
        }
    }
}

// ssrc stores BYTE offsets (src * 128) for the fp16 row gather.
__global__ void __launch_bounds__(256) kfinal(
        const int* __restrict__ pairs, const int* __restrict__ gbs,
        int* __restrict__ rs, int* __restrict__ ssrc, int N) {
    __shared__ int lcnt[512];
    __shared__ int lcur[512];
    __shared__ int ps[256];
    const int b = blockIdx.x;
    const int t = threadIdx.x;
    const int n0 = b << 9;
    const int e0 = gbs[b], e1 = gbs[b + 1];
    lcnt[t] = 0;
    lcnt[t + 256] = 0;
    __syncthreads();
    for (int e = e0 + t; e < e1; e += 256)
        atomicAdd(&lcnt[pairs[e] & 511], 1);
    __syncthreads();
    int c0 = lcnt[2 * t], c1 = lcnt[2 * t + 1];
    int sum = c0 + c1;
    ps[t] = sum;
    __syncthreads();
    for (int off = 1; off < 256; off <<= 1) {
        int add = (t >= off) ? ps[t - off] : 0;
        __syncthreads();
        ps[t] += add;
        __syncthreads();
    }
    int excl = ps[t] - sum;
    lcur[2 * t] = excl;
    lcur[2 * t + 1] = excl + c0;
    int n = n0 + 2 * t;
    if (n < N) rs[n] = e0 + excl;
    if (n + 1 < N) rs[n + 1] = e0 + excl + c0;
    __syncthreads();
    for (int e = e0 + t; e < e1; e += 256) {
        int p = pairs[e];
        int pos = atomicAdd(&lcur[p & 511], 1);
        ssrc[e0 + pos] = (int)((unsigned)p >> 9) << 7;   // byte offset of fp16 row
    }
}

// ---------------- fp32 x -> fp16 plane ----------------

__global__ void kcvt(const float* __restrict__ x, half_t* __restrict__ phi, int n4) {
    int i = blockIdx.x * blockDim.x + threadIdx.x;
    if (i < n4) {
        f32x4 v = ((const f32x4*)x)[i];
        h16x4 hi;
#pragma unroll
        for (int c = 0; c < 4; ++c) hi[c] = (half_t)v[c];
        ((h16x4*)phi)[i] = hi;
    }
}

// ---------------- weight prep: fp16 hi/lo MFMA B-fragments ----------------
// B[k][j], k in [0,128): k<64 -> Wl[j][k]; k>=64 -> Wr[j][k-64]
// frag f = (s*4+t)*2 (+1 for lo); element [lane][i]: k = s*32+(lane>>4)*8+i, j = t*16+(lane&15)

__global__ void kprepw(const float* __restrict__ Wl, const float* __restrict__ Wr,
                       half_t* __restrict__ Bf) {
    int id = blockIdx.x * blockDim.x + threadIdx.x;
    if (id >= 6 * 4 * 4 * 64 * 8) return;
    int i = id & 7;
    int lane = (id >> 3) & 63;
    int t = (id >> 9) & 3;
    int s = (id >> 11) & 3;
    int layer = id >> 13;
    int k = s * 32 + (lane >> 4) * 8 + i;
    int j = t * 16 + (lane & 15);
    float v = (k < 64) ? Wl[(layer * 64 + j) * 64 + k]
                       : Wr[(layer * 64 + j) * 64 + (k - 64)];
    half_t hi = (half_t)v;
    half_t lo = (half_t)(v - (float)hi);
    int f = (s * 4 + t) * 2;
    int base = layer * 16384 + f * 512 + lane * 8 + i;
    Bf[base] = hi;
    Bf[base + 512] = lo;
}

// ---------------- DE-FUSED aggregation: depth-8 pipelined gather, NO MFMA ----------------
// r10/r11 POST-MORTEM: the fused kernel is register-starved — with MFMA present the
// allocator caps arch VGPRs at ~half the wave budget (64@128, 84@170, measured r3/r4),
// and a latency-chain-beating pipeline (depth-8, confirmed faster even while spilling
// 100MB in r10) needs ~92 arch regs. De-fused: no MFMA -> no AGPR split -> full 128-reg
// budget at (256,4), depth-8 fits with margin, 16 waves/CU (2x the fused occupancy).
// Layout (r0-proven): wave owns 8 rows (r8 = lane>>3), lane sub8 = lane&7 owns one 16B
// slice; one load instr = 8 edges x 128B full rows. Per iteration: 8 independent gathers
// in flight + next-8 offset prefetch issued behind them; finished row-groups are
// exec-masked (no wasted traffic). Stores: contiguous 1KB/wave.

__global__ void __launch_bounds__(256, 4) kagg(
        const half_t* __restrict__ h16, const int* __restrict__ rs,
        const int* __restrict__ soff, half_t* __restrict__ agg16, int N) {
    const int lane = threadIdx.x & 63;
    const int wv = (blockIdx.x * blockDim.x + threadIdx.x) >> 6;
    const int row = wv * 8 + (lane >> 3);
    const int sub = lane & 7;
    if (row >= N) return;
    const char* hb = (const char*)h16 + sub * 16;
    const int beg = rs[row], end = rs[row + 1];
    const half_t NEG = (half_t)(-65504.0f);
    half8 a0 = {NEG, NEG, NEG, NEG, NEG, NEG, NEG, NEG};
    half8 a1 = a0, a2 = a0, a3 = a0, a4 = a0, a5 = a0, a6 = a0, a7 = a0;
    if (end > beg) {
        int lastE = end - 1;
        // prologue: first 8 offsets (clamped; re-max of a seen edge is a no-op)
        int o0 = soff[beg];
        int o1 = soff[(beg + 1 <= lastE) ? beg + 1 : lastE];
        int o2 = soff[(beg + 2 <= lastE) ? beg + 2 : lastE];
        int o3 = soff[(beg + 3 <= lastE) ? beg + 3 : lastE];
        int o4 = soff[(beg + 4 <= lastE) ? beg + 4 : lastE];
        int o5 = soff[(beg + 5 <= lastE) ? beg + 5 : lastE];
        int o6 = soff[(beg + 6 <= lastE) ? beg + 6 : lastE];
        int o7 = soff[(beg + 7 <= lastE) ? beg + 7 : lastE];
        for (int e = beg; e < end; e += 8) {
            // issue 8 independent gathers (one per edge of this row)
            half8 g0 = *(const half8*)(hb + o0);
            half8 g1 = *(const half8*)(hb + o1);
            half8 g2 = *(const half8*)(hb + o2);
            half8 g3 = *(const half8*)(hb + o3);
            half8 g4 = *(const half8*)(hb + o4);
            half8 g5 = *(const half8*)(hb + o5);
            half8 g6 = *(const half8*)(hb + o6);
            half8 g7 = *(const half8*)(hb + o7);
            // prefetch next iteration's offsets (stay in flight past the folds)
            int ne = e + 8;
            int q0 = soff[(ne     <= lastE) ? ne     : lastE];
            int q1 = soff[(ne + 1 <= lastE) ? ne + 1 : lastE];
            int q2 = soff[(ne + 2 <= lastE) ? ne + 2 : lastE];
            int q3 = soff[(ne + 3 <= lastE) ? ne + 3 : lastE];
            int q4 = soff[(ne + 4 <= lastE) ? ne + 4 : lastE];
            int q5 = soff[(ne + 5 <= lastE) ? ne + 5 : lastE];
            int q6 = soff[(ne + 6 <= lastE) ? ne + 6 : lastE];
            int q7 = soff[(ne + 7 <= lastE) ? ne + 7 : lastE];
            a0 = hmax8(a0, g0);
            a1 = hmax8(a1, g1);
            a2 = hmax8(a2, g2);
            a3 = hmax8(a3, g3);
            a4 = hmax8(a4, g4);
            a5 = hmax8(a5, g5);
            a6 = hmax8(a6, g6);
            a7 = hmax8(a7, g7);
            o0 = q0; o1 = q1; o2 = q2; o3 = q3;
            o4 = q4; o5 = q5; o6 = q6; o7 = q7;
        }
        a0 = hmax8(hmax8(hmax8(a0, a1), hmax8(a2, a3)),
                   hmax8(hmax8(a4, a5), hmax8(a6, a7)));
    } else {
        half8 z = {(half_t)0.f, (half_t)0.f, (half_t)0.f, (half_t)0.f,
                   (half_t)0.f, (half_t)0.f, (half_t)0.f, (half_t)0.f};
        a0 = z;                                  // no in-edges -> 0 (PyG convention)
    }
    *(half8*)((char*)agg16 + (size_t)row * 128 + sub * 16) = a0;
}

// ---------------- GEMM: fp16 A (agg + h streaming), fp16 hi/lo weights in LDS ----------------
// A-frag for 16x16x32_f16: lane (quad,lrow) reads agg16/hin row m0+lrow slices quad*16, +64.
// Rows m0..m0+15 are CONSECUTIVE -> the whole A-tile is 2KB contiguous (streaming, not
// gather). Live state ~50 arch regs -> no spill at (256,3)=85-reg cap. LDS 32KB x 3 = 96KB.

__global__ void __launch_bounds__(256, 3) kgemm(
        const half_t* __restrict__ agg16, const half_t* __restrict__ hin,
        const half_t* __restrict__ Bf, const float* __restrict__ bias,
        float* __restrict__ out32, half_t* __restrict__ hout, int N, int last) {
    __shared__ half_t Bs[16384];                  // 32 KB: 32 frags x 512 halfs
    const int tid = threadIdx.x;
    const int lane = tid & 63;
    const int quad = lane >> 4;
    const int lrow = lane & 15;
    const int wv = (blockIdx.x * blockDim.x + tid) >> 6;
    const int nwv = (gridDim.x * blockDim.x) >> 6;
    const int ntiles = (N + 15) >> 4;

    // stage weights: 2048 half8 elements, 8 per thread, coalesced
    {
        const half8* __restrict__ Bg = (const half8*)Bf;
        half8* Bsh = (half8*)Bs;
#pragma unroll
        for (int i = 0; i < 8; ++i)
            Bsh[i * 256 + tid] = Bg[i * 256 + tid];
    }
    __syncthreads();
    const half8* __restrict__ Bls = (const half8*)Bs;

    for (int tile = wv; tile < ntiles; tile += nwv) {
        const int m0 = tile << 4;
        int row = m0 + lrow;
        if (row >= N) row = N - 1;
        const char* pa = (const char*)agg16 + (size_t)row * 128 + quad * 16;
        const char* ph = (const char*)hin   + (size_t)row * 128 + quad * 16;
        half8 Aa0 = *(const half8*)(pa);
        half8 Aa1 = *(const half8*)(pa + 64);
        half8 Hh0 = *(const half8*)(ph);
        half8 Hh1 = *(const half8*)(ph + 64);

        f32x4 acc[4] = {{0.f, 0.f, 0.f, 0.f}, {0.f, 0.f, 0.f, 0.f},
                        {0.f, 0.f, 0.f, 0.f}, {0.f, 0.f, 0.f, 0.f}};
#pragma unroll
        for (int t = 0; t < 4; ++t) {
            int f = t * 2;                      // (s*4+t)*2 for s=0..3 below
            acc[t] = __builtin_amdgcn_mfma_f32_16x16x32_f16(Aa0, Bls[(f     ) * 64 + lane],      acc[t], 0, 0, 0);
            acc[t] = __builtin_amdgcn_mfma_f32_16x16x32_f16(Aa0, Bls[(f     ) * 64 + 64 + lane], acc[t], 0, 0, 0);
            acc[t] = __builtin_amdgcn_mfma_f32_16x16x32_f16(Aa1, Bls[(f +  8) * 64 + lane],      acc[t], 0, 0, 0);
            acc[t] = __builtin_amdgcn_mfma_f32_16x16x32_f16(Aa1, Bls[(f +  8) * 64 + 64 + lane], acc[t], 0, 0, 0);
            acc[t] = __builtin_amdgcn_mfma_f32_16x16x32_f16(Hh0, Bls[(f + 16) * 64 + lane],      acc[t], 0, 0, 0);
            acc[t] = __builtin_amdgcn_mfma_f32_16x16x32_f16(Hh0, Bls[(f + 16) * 64 + 64 + lane], acc[t], 0, 0, 0);
            acc[t] = __builtin_amdgcn_mfma_f32_16x16x32_f16(Hh1, Bls[(f + 24) * 64 + lane],      acc[t], 0, 0, 0);
            acc[t] = __builtin_amdgcn_mfma_f32_16x16x32_f16(Hh1, Bls[(f + 24) * 64 + 64 + lane], acc[t], 0, 0, 0);
        }

        // C/D: col = t*16 + lrow, row = m0 + quad*4 + r
#pragma unroll
        for (int t = 0; t < 4; ++t) {
            int col = t * 16 + lrow;
            float bsv = bias[t * 16 + lrow];
#pragma unroll
            for (int r = 0; r < 4; ++r) {
                int orow = m0 + quad * 4 + r;
                if (orow < N) {
                    float v = acc[t][r] + bsv;
                    if (!last) {
                        v = fmaxf(v, 0.0f);
                        hout[(size_t)orow * DIM + col] = (half_t)v;
                    } else {
                        out32[(size_t)orow * DIM + col] = v;
                    }
                }
            }
        }
    }
}

// ---------------- host ----------------

extern "C" void kernel_launch(void* const* d_in, const int* in_sizes, int n_in,
                              void* d_out, int out_size, void* d_ws, size_t ws_size,
                              hipStream_t stream) {
    const float* x  = (const float*)d_in[0];
    const int*   ei = (const int*)d_in[1];
    const float* Wl = (const float*)d_in[2];
    const float* bl = (const float*)d_in[3];
    const float* Wr = (const float*)d_in[4];
    int N = in_sizes[0] / DIM;
    int E = in_sizes[1] / 2;

    size_t nd = (size_t)N * DIM;
    half_t* p0    = (half_t*)d_ws;           // fp16 h ping
    half_t* p1    = p0 + nd;                 // fp16 h pong
    half_t* agg16 = p1 + nd;                 // nd halfs; aliased as `pairs` during CSR build
    int*    rs    = (int*)(agg16 + nd);      // N+1 used, N+4 reserved
    int*    ssrc  = rs + (N + 4);            // byte offsets
    int*    gcnt  = ssrc + E;                // 256
    int*    gbs   = gcnt + 256;              // NB+1 (260 reserved)
    int*    gbc   = gbs + 260;               // 256
    half_t* Bf    = (half_t*)(gbc + 256);    // 6 layers * 16384 halfs

    int NB = (N + 511) >> 9;                 // 196 for N=100000
    int* pairs = (int*)agg16;                // consumed by kfinal before layer 0 writes agg16

    hipMemsetAsync(gcnt, 0, 256 * sizeof(int), stream);
    kbcnt<<<640, 256, 0, stream>>>(ei, E, gcnt);
    kbscan<<<1, 256, 0, stream>>>(gcnt, gbs, gbc, NB, E, rs, N);
    kbin<<<(E + 4095) / 4096, 256, 0, stream>>>(ei, E, gbc, pairs, NB);
    kfinal<<<NB, 256, 0, stream>>>(pairs, gbs, rs, ssrc, N);
    kprepw<<<(6 * 4 * 4 * 64 * 8 + 255) / 256, 256, 0, stream>>>(Wl, Wr, Bf);
    kcvt<<<((int)(nd / 4) + 255) / 256, 256, 0, stream>>>(x, p0, (int)(nd / 4));

    for (int l = 0; l < 6; ++l) {
        half_t* ih = (l & 1) ? p1 : p0;
        half_t* oh = (l & 1) ? p0 : p1;
        int last = (l == 5);
        kagg<<<(N + 31) / 32, 256, 0, stream>>>(ih, rs, ssrc, agg16, N);
        kgemm<<<512, 256, 0, stream>>>(agg16, ih, Bf + l * 16384, bl + l * 64,
                                       (float*)d_out, oh, N, last);
    }
}